// Round 5
// baseline (740.405 us; speedup 1.0000x reference)
//
#include <hip/hip_runtime.h>
#include <hip/hip_bf16.h>
#include <math.h>

#define BATCH 128
#define SEQ   200
#define HID   1024
#define NH    4
#define DK    256
#define NF    101    // SEQ/2+1
#define NF2   202    // stacked real+imag rows
#define LS    200
#define PD    256    // padded s / fidx / l dimension

typedef __attribute__((ext_vector_type(8))) short bf16x8;
typedef __attribute__((ext_vector_type(4))) float f32x4;

__device__ __forceinline__ unsigned short f2bf(float f) {
    union { float f; unsigned u; } v; v.f = f;
    unsigned r = v.u + 0x7fff + ((v.u >> 16) & 1);
    return (unsigned short)(r >> 16);
}
__device__ __forceinline__ float bf2f(unsigned short h) {
    union { unsigned u; float f; } v; v.u = ((unsigned)h) << 16;
    return v.f;
}

__device__ __forceinline__ void gld_lds16(const void* g, void* l) {
    __builtin_amdgcn_global_load_lds(
        (const __attribute__((address_space(1))) unsigned*)g,
        (__attribute__((address_space(3))) unsigned*)l, 16, 0, 0);
}

// ---------------------------------------------------------------------------
// Tables, padded to 256x256, pad = 0 (see round-2 derivation).
// ---------------------------------------------------------------------------
__global__ void init_tables_bf16(unsigned short* __restrict__ F, unsigned short* __restrict__ G) {
    int idx = blockIdx.x * 256 + threadIdx.x;
    const double inv = 0.07071067811865475244;
    const double PI2 = 6.283185307179586476925;
    {
        int fidx = idx >> 8, s = idx & 255;
        double v = 0.0;
        if (s < SEQ && fidx < NF2) {
            int f = (fidx < NF) ? fidx : fidx - NF;
            double ang = PI2 * (double)((f * s) % SEQ) / (double)SEQ;
            v = (fidx < NF) ? cos(ang) * inv : -sin(ang) * inv;
        }
        F[idx] = f2bf((float)v);
    }
    {
        int s = idx >> 8, j = idx & 255;
        double v = 0.0;
        if (s < SEQ && j < NF2) {
            if (j < NF) {
                double al = (j == 0 || j == NF - 1) ? 1.0 : 2.0;
                v = al * cos(PI2 * (double)((j * s) % SEQ) / (double)SEQ) * inv;
            } else {
                int f = j - NF;
                if (f != 0 && f != NF - 1)
                    v = -2.0 * sin(PI2 * (double)((f * s) % SEQ) / (double)SEQ) * inv;
            }
        }
        G[idx] = f2bf((float)v);
    }
}

__global__ void wtrans256(const float* __restrict__ src, unsigned short* __restrict__ dst) {
    int dout = blockIdx.x, din = threadIdx.x;
    dst[dout * 256 + din] = f2bf(src[din * 256 + dout]);
}

__global__ void w3pad(const float* __restrict__ src, unsigned short* __restrict__ dst) {
    int row = blockIdx.x, col = threadIdx.x;
    dst[row * 256 + col] = (row < LS) ? f2bf(src[row * 256 + col]) : (unsigned short)0;
}

__global__ void fconv(const float* __restrict__ src, unsigned short* __restrict__ dst, int n) {
    int i = blockIdx.x * 256 + threadIdx.x;
    if (i < n) dst[i] = f2bf(src[i]);
}

// ---------------------------------------------------------------------------
// Proj GEMM (round-2 structure, B = fp32 reg-staged with convert). 128x128,
// BK=64, single-buffer, 32KB LDS.
// ---------------------------------------------------------------------------
__global__ __launch_bounds__(256)
void mgemm128(const unsigned short* __restrict__ A, const float* __restrict__ Bf0,
              unsigned short* __restrict__ C0,
              int K, int lda, int ldb, int ldc,
              long aOuter, long aInner, long bOuter, long bInner,
              long cOuter, long cInner, int nInner, int nbValid) {
    int bz = blockIdx.z;
    int bo = bz / nInner, bi = bz - bo * nInner;
    const unsigned short* Ab = A + bo * aOuter + bi * aInner;
    const float* Bf = Bf0 + bo * bOuter + bi * bInner;

    __shared__ unsigned short As[128 * 64];
    __shared__ unsigned short Bs[128 * 64];

    int t = threadIdx.x;
    int m0 = blockIdx.y * 128, n0 = blockIdx.x * 128;
    int lane = t & 63, wave = t >> 6;
    int wr = wave >> 1, wc = wave & 1;
    int la = lane & 15, hi = lane >> 4;

    f32x4 acc[4][4] = {};
    int rsub = t >> 3;
    int c8 = (t & 7) * 8;

    for (int k0 = 0; k0 < K; k0 += 64) {
#pragma unroll
        for (int p = 0; p < 4; ++p) {
            int row = p * 32 + rsub;
            gld_lds16(Ab + (long)(m0 + row) * lda + k0 + c8, &As[row * 64 + c8]);
        }
#pragma unroll
        for (int p = 0; p < 4; ++p) {
            int row = p * 32 + rsub;
            int gn = n0 + row;
            unsigned short tmp[8];
            if (gn < nbValid) {
                const float4* src = reinterpret_cast<const float4*>(Bf + (long)gn * ldb + k0 + c8);
                float4 x0 = src[0], x1 = src[1];
                tmp[0] = f2bf(x0.x); tmp[1] = f2bf(x0.y); tmp[2] = f2bf(x0.z); tmp[3] = f2bf(x0.w);
                tmp[4] = f2bf(x1.x); tmp[5] = f2bf(x1.y); tmp[6] = f2bf(x1.z); tmp[7] = f2bf(x1.w);
            } else {
#pragma unroll
                for (int j = 0; j < 8; ++j) tmp[j] = 0;
            }
            *(bf16x8*)&Bs[row * 64 + c8] = *(bf16x8*)tmp;
        }
        __syncthreads();
#pragma unroll
        for (int half = 0; half < 2; ++half) {
            int ko = half * 32 + hi * 8;
            bf16x8 a[4], b[4];
#pragma unroll
            for (int mi = 0; mi < 4; ++mi)
                a[mi] = *(const bf16x8*)&As[(wr * 64 + mi * 16 + la) * 64 + ko];
#pragma unroll
            for (int ni = 0; ni < 4; ++ni)
                b[ni] = *(const bf16x8*)&Bs[(wc * 64 + ni * 16 + la) * 64 + ko];
#pragma unroll
            for (int mi = 0; mi < 4; ++mi)
#pragma unroll
                for (int ni = 0; ni < 4; ++ni)
                    acc[mi][ni] = __builtin_amdgcn_mfma_f32_16x16x32_bf16(a[mi], b[ni], acc[mi][ni], 0, 0, 0);
        }
        __syncthreads();
    }

    unsigned short* Ch = C0 + bo * cOuter + bi * cInner;
#pragma unroll
    for (int mi = 0; mi < 4; ++mi) {
#pragma unroll
        for (int ni = 0; ni < 4; ++ni) {
            int gn = n0 + wc * 64 + ni * 16 + la;
            int gmB = m0 + wr * 64 + mi * 16 + hi * 4;
#pragma unroll
            for (int rr = 0; rr < 4; ++rr)
                Ch[(long)(gmB + rr) * ldc + gn] = f2bf(acc[mi][ni][rr]);
        }
    }
}

// ---------------------------------------------------------------------------
// Counted-vmcnt 2-deep pipelined bf16 MFMA GEMM (T4, m218 pattern):
// 128x128 tile, BK=64, LDS 2x32KB. NO __syncthreads in the K-loop: raw
// s_barrier + per-thread `s_waitcnt vmcnt(8)` (waits only the PREVIOUS
// tile's 8 global_load_lds; the just-issued prefetch stays in flight
// across both barriers). Safety: every thread waits its own 8 loads
// before barrier1 => buf[cur] collectively complete; ds_reads are all
// consumed by MFMAs before barrier2 => WAR on buf is safe.
// EPI: 0 bf16; 2 relu(acc+biasN)->bf16; 4 (acc+biasN)->bf16.
// C rows >= mValid not written. XCDSWZ: bijective %8 swizzle (grid%8==0).
// ---------------------------------------------------------------------------
template <int EPI, bool XCDSWZ>
__global__ __launch_bounds__(256)
void mgemm128c(const unsigned short* __restrict__ A, const unsigned short* __restrict__ B,
               unsigned short* __restrict__ C0, int K, int lda, int ldb, int ldc,
               long aOuter, long aInner, long bOuter, long bInner,
               long cOuter, long cInner, int nInner, int mValid,
               const float* __restrict__ biasN) {
    int bx = blockIdx.x, by = blockIdx.y;
    if (XCDSWZ) {
        int nwg = gridDim.x * gridDim.y;
        int flat = by * gridDim.x + bx;
        int cpx = nwg >> 3;
        int swz = (flat & 7) * cpx + (flat >> 3);
        bx = swz % gridDim.x; by = swz / gridDim.x;
    }
    int bz = blockIdx.z;
    int bo = bz / nInner, bi = bz - bo * nInner;
    const unsigned short* Ab = A + bo * aOuter + bi * aInner;
    const unsigned short* Bb = B + bo * bOuter + bi * bInner;

    __shared__ unsigned short As[2][128 * 64];
    __shared__ unsigned short Bs[2][128 * 64];

    int t = threadIdx.x;
    int m0 = by * 128, n0 = bx * 128;
    int lane = t & 63, wave = t >> 6;
    int wr = wave >> 1, wc = wave & 1;
    int la = lane & 15, hi = lane >> 4;

    f32x4 acc[4][4] = {};
    int rsub = t >> 3;
    int c8 = (t & 7) * 8;

    auto STAGE = [&](int buf, int k0) {
#pragma unroll
        for (int p = 0; p < 4; ++p) {
            int row = p * 32 + rsub;
            gld_lds16(Ab + (long)(m0 + row) * lda + k0 + c8, &As[buf][row * 64 + c8]);
            gld_lds16(Bb + (long)(n0 + row) * ldb + k0 + c8, &Bs[buf][row * 64 + c8]);
        }
    };

    int ktiles = K >> 6;
    STAGE(0, 0);

    for (int kt = 0; kt < ktiles; ++kt) {
        int cur = kt & 1;
        if (kt + 1 < ktiles) {
            STAGE(cur ^ 1, (kt + 1) << 6);
            asm volatile("s_waitcnt vmcnt(8)" ::: "memory");   // prev tile landed
        } else {
            asm volatile("s_waitcnt vmcnt(0)" ::: "memory");
        }
        __builtin_amdgcn_s_barrier();          // buf[cur] ready for all
#pragma unroll
        for (int half = 0; half < 2; ++half) {
            int ko = half * 32 + hi * 8;
            bf16x8 a[4], b[4];
#pragma unroll
            for (int mi = 0; mi < 4; ++mi)
                a[mi] = *(const bf16x8*)&As[cur][(wr * 64 + mi * 16 + la) * 64 + ko];
#pragma unroll
            for (int ni = 0; ni < 4; ++ni)
                b[ni] = *(const bf16x8*)&Bs[cur][(wc * 64 + ni * 16 + la) * 64 + ko];
            __builtin_amdgcn_s_setprio(1);
#pragma unroll
            for (int mi = 0; mi < 4; ++mi)
#pragma unroll
                for (int ni = 0; ni < 4; ++ni)
                    acc[mi][ni] = __builtin_amdgcn_mfma_f32_16x16x32_bf16(a[mi], b[ni], acc[mi][ni], 0, 0, 0);
            __builtin_amdgcn_s_setprio(0);
        }
        __builtin_amdgcn_s_barrier();          // all reads of buf[cur] done
    }

    unsigned short* Ch = C0 + bo * cOuter + bi * cInner;
#pragma unroll
    for (int mi = 0; mi < 4; ++mi) {
#pragma unroll
        for (int ni = 0; ni < 4; ++ni) {
            int gn = n0 + wc * 64 + ni * 16 + la;
            int gmB = m0 + wr * 64 + mi * 16 + hi * 4;
            float bN = 0.f;
            if (EPI == 2 || EPI == 4) bN = biasN[gn];
#pragma unroll
            for (int rr = 0; rr < 4; ++rr) {
                int gm = gmB + rr;
                if (gm >= mValid) continue;
                float v = acc[mi][ni][rr];
                if (EPI == 0) Ch[(long)gm * ldc + gn] = f2bf(v);
                else if (EPI == 2) Ch[(long)gm * ldc + gn] = f2bf(fmaxf(v + bN, 0.f));
                else Ch[(long)gm * ldc + gn] = f2bf(v + bN);
            }
        }
    }
}

// ---------------------------------------------------------------------------
// cross-spectrum * complex weight, IN PLACE on QF. (bh, d, 256) layout.
// ---------------------------------------------------------------------------
__global__ void crossspec(unsigned short* __restrict__ QF, const unsigned short* __restrict__ KF,
                          const float* __restrict__ cw) {
    long idx = (long)blockIdx.x * 256 + threadIdx.x;
    if (idx >= (long)BATCH * NH * DK * NF) return;
    int f = (int)(idx % NF);
    long tq = idx / NF;
    int d = (int)(tq % DK);
    int bh = (int)(tq / DK);
    int h = bh & (NH - 1);
    long base = (long)bh * DK * PD + (long)d * PD;
    float qr = bf2f(QF[base + f]), qi = bf2f(QF[base + NF + f]);
    float kr = bf2f(KF[base + f]), ki = bf2f(KF[base + NF + f]);
    float cr = qr * kr + qi * ki;
    float ci = qi * kr - qr * ki;
    long wb = (((long)h * NF + f) * DK + d) * 2;
    float wr = cw[wb], wi = cw[wb + 1];
    QF[base + f]      = f2bf(cr * wr - ci * wi);
    QF[base + NF + f] = f2bf(cr * wi + ci * wr);
    if (f < PD - NF2) QF[base + NF2 + f] = 0;
}

// ---------------------------------------------------------------------------
// softmax over contiguous s (cols 0..199 of 256), bf16 in -> bf16 out
// ---------------------------------------------------------------------------
__global__ __launch_bounds__(256) void softmax_rows(const unsigned short* __restrict__ in,
                                                    unsigned short* __restrict__ out) {
    long row = (long)blockIdx.x * 4 + (threadIdx.x >> 6);
    int lane = threadIdx.x & 63;
    const unsigned short* p = in + row * PD;
    float v[4];
    float m = -1e30f;
#pragma unroll
    for (int i = 0; i < 4; ++i) {
        int s = lane + 64 * i;
        v[i] = (s < SEQ) ? bf2f(p[s]) : -1e30f;
        m = fmaxf(m, v[i]);
    }
#pragma unroll
    for (int o = 32; o; o >>= 1) m = fmaxf(m, __shfl_xor(m, o));
    float e[4], sum = 0.f;
#pragma unroll
    for (int i = 0; i < 4; ++i) {
        int s = lane + 64 * i;
        e[i] = (s < SEQ) ? expf(v[i] - m) : 0.f;
        sum += e[i];
    }
#pragma unroll
    for (int o = 32; o; o >>= 1) sum += __shfl_xor(sum, o);
    float inv = 1.f / sum;
    unsigned short* q = out + row * PD;
#pragma unroll
    for (int i = 0; i < 4; ++i) {
        int s = lane + 64 * i;
        q[s] = (s < SEQ) ? f2bf(e[i] * inv) : (unsigned short)0;
    }
}

// ---------------------------------------------------------------------------
// gelu(erf) + TF LayerNorm per 1024-wide row (bf16 in, fp32 out)
// ---------------------------------------------------------------------------
__global__ __launch_bounds__(256) void gelu_ln_kernel(const unsigned short* __restrict__ y2,
                               const float* __restrict__ lnw, const float* __restrict__ lnb,
                               float* __restrict__ out) {
    long row = blockIdx.x;
    int tid = threadIdx.x;
    const short4* xr = reinterpret_cast<const short4*>(y2 + row * HID);
    short4 h4 = xr[tid];
    float g[4];
    {
        float x0 = bf2f((unsigned short)h4.x), x1 = bf2f((unsigned short)h4.y);
        float x2 = bf2f((unsigned short)h4.z), x3 = bf2f((unsigned short)h4.w);
        g[0] = 0.5f * x0 * (1.f + erff(x0 * 0.70710678118654752f));
        g[1] = 0.5f * x1 * (1.f + erff(x1 * 0.70710678118654752f));
        g[2] = 0.5f * x2 * (1.f + erff(x2 * 0.70710678118654752f));
        g[3] = 0.5f * x3 * (1.f + erff(x3 * 0.70710678118654752f));
    }

    __shared__ float red[4];
    float s = g[0] + g[1] + g[2] + g[3];
#pragma unroll
    for (int o = 32; o > 0; o >>= 1) s += __shfl_down(s, o);
    if ((tid & 63) == 0) red[tid >> 6] = s;
    __syncthreads();
    float mean = (red[0] + red[1] + red[2] + red[3]) * (1.f / (float)HID);

    float v2 = 0.f;
#pragma unroll
    for (int p = 0; p < 4; ++p) { float d = g[p] - mean; v2 += d * d; }
    __syncthreads();
#pragma unroll
    for (int o = 32; o > 0; o >>= 1) v2 += __shfl_down(v2, o);
    if ((tid & 63) == 0) red[tid >> 6] = v2;
    __syncthreads();
    float var = (red[0] + red[1] + red[2] + red[3]) * (1.f / (float)HID);
    float rstd = rsqrtf(var + 1e-12f);

    float4 o4;
    int i0 = tid * 4;
    o4.x = (g[0] - mean) * rstd * lnw[i0 + 0] + lnb[i0 + 0];
    o4.y = (g[1] - mean) * rstd * lnw[i0 + 1] + lnb[i0 + 1];
    o4.z = (g[2] - mean) * rstd * lnw[i0 + 2] + lnb[i0 + 2];
    o4.w = (g[3] - mean) * rstd * lnw[i0 + 3] + lnb[i0 + 3];
    reinterpret_cast<float4*>(out + row * HID)[tid] = o4;
}

// ---------------------------------------------------------------------------
extern "C" void kernel_launch(void* const* d_in, const int* in_sizes, int n_in,
                              void* d_out, int out_size, void* d_ws, size_t ws_size,
                              hipStream_t stream) {
    const float* query = (const float*)d_in[0];
    const float* key   = (const float*)d_in[1];
    const float* value = (const float*)d_in[2];
    const float* w0 = (const float*)d_in[3];
    const float* w1 = (const float*)d_in[4];
    const float* w2 = (const float*)d_in[5];
    const float* w3 = (const float*)d_in[6];
    const float* attn_bias = (const float*)d_in[7];
    const float* cw = (const float*)d_in[8];
    const float* lw = (const float*)d_in[9];
    const float* lb = (const float*)d_in[10];
    const float* lnw = (const float*)d_in[11];
    const float* lnb = (const float*)d_in[12];
    float* out = (float*)d_out;

    char* base = (char*)d_ws;
    const long BH = (long)BATCH * NH;
    const long SZR = (long)BH * PD * PD;          // elements per 64MiB bf16 region
    const size_t M64 = 67108864;

    unsigned short* F_stack = (unsigned short*)(base + 0);
    unsigned short* G_stack = (unsigned short*)(base + 131072);
    unsigned short* w0T = (unsigned short*)(base + 262144);
    unsigned short* w1T = (unsigned short*)(base + 393216);
    unsigned short* w2T = (unsigned short*)(base + 524288);
    unsigned short* w3b = (unsigned short*)(base + 655360);
    unsigned short* lwb = (unsigned short*)(base + 786432);   // 2MiB
    char* rA = base + 4194304;            // qpT -> corr
    char* rB = rA + M64;                  // kpT -> probs
    char* rC = rB + M64;                  // vpT
    char* rD = rC + M64;                  // QF/R -> alphaT(bf16) -> y2(bf16)
    char* rE = rD + M64;                  // KF   -> X

    unsigned short* qpT = (unsigned short*)rA;
    unsigned short* kpT = (unsigned short*)rB;
    unsigned short* vpT = (unsigned short*)rC;
    unsigned short* QF  = (unsigned short*)rD;
    unsigned short* KF  = (unsigned short*)rE;
    unsigned short* corr = (unsigned short*)rA;
    unsigned short* alphaT = (unsigned short*)rD;
    unsigned short* probs = (unsigned short*)rB;
    unsigned short* X  = (unsigned short*)rE;
    unsigned short* y2 = (unsigned short*)rD;

    // tables + weight conversion
    init_tables_bf16<<<256, 256, 0, stream>>>(F_stack, G_stack);
    wtrans256<<<256, 256, 0, stream>>>(w0, w0T);
    wtrans256<<<256, 256, 0, stream>>>(w1, w1T);
    wtrans256<<<256, 256, 0, stream>>>(w2, w2T);
    w3pad<<<256, 256, 0, stream>>>(w3, w3b);
    fconv<<<(HID * HID + 255) / 256, 256, 0, stream>>>(lw, lwb, HID * HID);

    // projections: qpT[bh](d,s) = w0T @ q^T ; B = raw fp32 rows (s<200 valid)
    dim3 gproj(2, 2, BH);
    mgemm128<<<gproj, 256, 0, stream>>>(w0T, query, qpT, DK, DK, HID, PD,
        0L, 0L, (long)SEQ * HID, (long)DK, (long)NH * PD * PD, (long)PD * PD, NH, SEQ);
    mgemm128<<<gproj, 256, 0, stream>>>(w1T, key, kpT, DK, DK, HID, PD,
        0L, 0L, (long)SEQ * HID, (long)DK, (long)NH * PD * PD, (long)PD * PD, NH, SEQ);
    mgemm128<<<gproj, 256, 0, stream>>>(w2T, value, vpT, DK, DK, HID, PD,
        0L, 0L, (long)SEQ * HID, (long)DK, (long)NH * PD * PD, (long)PD * PD, NH, SEQ);

    // forward DFT (q and k batched via bo): QF[bh](d,f) = qpT @ F^T
    dim3 gfwd(2, 2, 2 * BH);
    mgemm128c<0, false><<<gfwd, 256, 0, stream>>>(qpT, F_stack, QF, PD, PD, PD, PD,
        SZR, (long)PD * PD, 0L, 0L, SZR, (long)PD * PD, (int)BH, PD, nullptr);

    // cross-spectrum * weight (in place on QF)
    long ncs = (long)BH * DK * NF;
    crossspec<<<(unsigned)((ncs + 255) / 256), 256, 0, stream>>>(QF, KF, cw);

    // inverse DFT: corr[bh](s,d) = G @ R^T, epilogue relu(+attn_bias over d)
    dim3 gstd(2, 2, BH);
    mgemm128c<2, false><<<gstd, 256, 0, stream>>>(G_stack, QF, corr, PD, PD, PD, PD,
        0L, 0L, (long)PD * PD, 0L, (long)PD * PD, 0L, 1, PD, attn_bias);

    // alphaT[bh](l,s) = w3b @ corr^T-form (bf16 out)
    mgemm128c<0, false><<<gstd, 256, 0, stream>>>(w3b, corr, alphaT, PD, PD, PD, PD,
        0L, 0L, (long)PD * PD, 0L, (long)PD * PD, 0L, 1, PD, nullptr);

    // softmax over contiguous s
    softmax_rows<<<(unsigned)(BH * PD / 4), 256, 0, stream>>>(alphaT, probs);

    // X[b, l, h*256+d] = probs(l,s) @ vpT(d,s)^T  -- direct, no transpose
    mgemm128c<0, false><<<gstd, 256, 0, stream>>>(probs, vpT, X, PD, PD, PD, HID,
        (long)NH * PD * PD, (long)PD * PD,
        (long)NH * PD * PD, (long)PD * PD,
        (long)LS * HID, (long)DK, NH, LS, nullptr);

    // y2 = X @ lw^T + lb : 25600 x 1024 x 1024  (bf16 out, XCD swizzle)
    dim3 glin(HID / 128, (BATCH * LS) / 128, 1);
    mgemm128c<4, true><<<glin, 256, 0, stream>>>(X, lwb, y2, HID, HID, HID, HID,
        0L, 0L, 0L, 0L, 0L, 0L, 1, BATCH * LS, lb);

    // gelu + LayerNorm
    gelu_ln_kernel<<<(unsigned)(BATCH * LS), 256, 0, stream>>>(y2, lnw, lnb, out);
}

// Round 6
// 700.597 us; speedup vs baseline: 1.0568x; 1.0568x over previous
//
#include <hip/hip_runtime.h>
#include <hip/hip_bf16.h>
#include <math.h>

#define BATCH 128
#define SEQ   200
#define HID   1024
#define NH    4
#define DK    256
#define NF    101    // SEQ/2+1
#define NF2   202    // stacked real+imag rows
#define LS    200
#define PD    256    // padded s / fidx / l dimension

typedef __attribute__((ext_vector_type(8))) short bf16x8;
typedef __attribute__((ext_vector_type(4))) float f32x4;

__device__ __forceinline__ unsigned short f2bf(float f) {
    union { float f; unsigned u; } v; v.f = f;
    unsigned r = v.u + 0x7fff + ((v.u >> 16) & 1);
    return (unsigned short)(r >> 16);
}
__device__ __forceinline__ float bf2f(unsigned short h) {
    union { unsigned u; float f; } v; v.u = ((unsigned)h) << 16;
    return v.f;
}

__device__ __forceinline__ void gld_lds16(const void* g, void* l) {
    __builtin_amdgcn_global_load_lds(
        (const __attribute__((address_space(1))) unsigned*)g,
        (__attribute__((address_space(3))) unsigned*)l, 16, 0, 0);
}

// ---------------------------------------------------------------------------
// Tables, padded to 256x256, pad = 0 (see round-2 derivation).
// ---------------------------------------------------------------------------
__global__ void init_tables_bf16(unsigned short* __restrict__ F, unsigned short* __restrict__ G) {
    int idx = blockIdx.x * 256 + threadIdx.x;
    const double inv = 0.07071067811865475244;
    const double PI2 = 6.283185307179586476925;
    {
        int fidx = idx >> 8, s = idx & 255;
        double v = 0.0;
        if (s < SEQ && fidx < NF2) {
            int f = (fidx < NF) ? fidx : fidx - NF;
            double ang = PI2 * (double)((f * s) % SEQ) / (double)SEQ;
            v = (fidx < NF) ? cos(ang) * inv : -sin(ang) * inv;
        }
        F[idx] = f2bf((float)v);
    }
    {
        int s = idx >> 8, j = idx & 255;
        double v = 0.0;
        if (s < SEQ && j < NF2) {
            if (j < NF) {
                double al = (j == 0 || j == NF - 1) ? 1.0 : 2.0;
                v = al * cos(PI2 * (double)((j * s) % SEQ) / (double)SEQ) * inv;
            } else {
                int f = j - NF;
                if (f != 0 && f != NF - 1)
                    v = -2.0 * sin(PI2 * (double)((f * s) % SEQ) / (double)SEQ) * inv;
            }
        }
        G[idx] = f2bf((float)v);
    }
}

__global__ void wtrans256(const float* __restrict__ src, unsigned short* __restrict__ dst) {
    int dout = blockIdx.x, din = threadIdx.x;
    dst[dout * 256 + din] = f2bf(src[din * 256 + dout]);
}

__global__ void w3pad(const float* __restrict__ src, unsigned short* __restrict__ dst) {
    int row = blockIdx.x, col = threadIdx.x;
    dst[row * 256 + col] = (row < LS) ? f2bf(src[row * 256 + col]) : (unsigned short)0;
}

__global__ void fconv(const float* __restrict__ src, unsigned short* __restrict__ dst, int n) {
    int i = blockIdx.x * 256 + threadIdx.x;
    if (i < n) dst[i] = f2bf(src[i]);
}

// T2 swizzle: LDS slot (row, c8) holds global k-offset (c8 ^ ((row&7)<<3)).
// Involution; 16B granularity; spreads the 128B-stride row reads over all
// 8 16B column slots (2-way residual = free). Rule #21: linear LDS dest +
// inverse-swizzled SOURCE (stage) + swizzled READ (frags).
#define KSWZ(row, c8) ((c8) ^ (((row) & 7) << 3))

// ---------------------------------------------------------------------------
// Proj GEMM (B = fp32 reg-staged with convert). 128x128, BK=64,
// single-buffer 32KB LDS, swizzled layout.
// ---------------------------------------------------------------------------
__global__ __launch_bounds__(256)
void mgemm128(const unsigned short* __restrict__ A, const float* __restrict__ Bf0,
              unsigned short* __restrict__ C0,
              int K, int lda, int ldb, int ldc,
              long aOuter, long aInner, long bOuter, long bInner,
              long cOuter, long cInner, int nInner, int nbValid) {
    int bz = blockIdx.z;
    int bo = bz / nInner, bi = bz - bo * nInner;
    const unsigned short* Ab = A + bo * aOuter + bi * aInner;
    const float* Bf = Bf0 + bo * bOuter + bi * bInner;

    __shared__ unsigned short As[128 * 64];
    __shared__ unsigned short Bs[128 * 64];

    int t = threadIdx.x;
    int m0 = blockIdx.y * 128, n0 = blockIdx.x * 128;
    int lane = t & 63, wave = t >> 6;
    int wr = wave >> 1, wc = wave & 1;
    int la = lane & 15, hi = lane >> 4;

    f32x4 acc[4][4] = {};
    int rsub = t >> 3;
    int c8 = (t & 7) * 8;

    for (int k0 = 0; k0 < K; k0 += 64) {
#pragma unroll
        for (int p = 0; p < 4; ++p) {
            int row = p * 32 + rsub;
            // A: linear LDS dest, inverse-swizzled global source
            gld_lds16(Ab + (long)(m0 + row) * lda + k0 + KSWZ(row, c8), &As[row * 64 + c8]);
        }
#pragma unroll
        for (int p = 0; p < 4; ++p) {
            int row = p * 32 + rsub;
            int gn = n0 + row;
            unsigned short tmp[8];
            if (gn < nbValid) {
                const float4* src = reinterpret_cast<const float4*>(Bf + (long)gn * ldb + k0 + c8);
                float4 x0 = src[0], x1 = src[1];
                tmp[0] = f2bf(x0.x); tmp[1] = f2bf(x0.y); tmp[2] = f2bf(x0.z); tmp[3] = f2bf(x0.w);
                tmp[4] = f2bf(x1.x); tmp[5] = f2bf(x1.y); tmp[6] = f2bf(x1.z); tmp[7] = f2bf(x1.w);
            } else {
#pragma unroll
                for (int j = 0; j < 8; ++j) tmp[j] = 0;
            }
            // B: reg-staged -> write directly to swizzled slot
            *(bf16x8*)&Bs[row * 64 + KSWZ(row, c8)] = *(bf16x8*)tmp;
        }
        __syncthreads();
#pragma unroll
        for (int half = 0; half < 2; ++half) {
            int ko = half * 32 + hi * 8;
            bf16x8 a[4], b[4];
#pragma unroll
            for (int mi = 0; mi < 4; ++mi) {
                int ra = wr * 64 + mi * 16 + la;
                a[mi] = *(const bf16x8*)&As[ra * 64 + KSWZ(ra, ko)];
            }
#pragma unroll
            for (int ni = 0; ni < 4; ++ni) {
                int rb = wc * 64 + ni * 16 + la;
                b[ni] = *(const bf16x8*)&Bs[rb * 64 + KSWZ(rb, ko)];
            }
#pragma unroll
            for (int mi = 0; mi < 4; ++mi)
#pragma unroll
                for (int ni = 0; ni < 4; ++ni)
                    acc[mi][ni] = __builtin_amdgcn_mfma_f32_16x16x32_bf16(a[mi], b[ni], acc[mi][ni], 0, 0, 0);
        }
        __syncthreads();
    }

    unsigned short* Ch = C0 + bo * cOuter + bi * cInner;
#pragma unroll
    for (int mi = 0; mi < 4; ++mi) {
#pragma unroll
        for (int ni = 0; ni < 4; ++ni) {
            int gn = n0 + wc * 64 + ni * 16 + la;
            int gmB = m0 + wr * 64 + mi * 16 + hi * 4;
#pragma unroll
            for (int rr = 0; rr < 4; ++rr)
                Ch[(long)(gmB + rr) * ldc + gn] = f2bf(acc[mi][ni][rr]);
        }
    }
}

// ---------------------------------------------------------------------------
// Counted-vmcnt 2-deep pipelined bf16 MFMA GEMM + T2 swizzle:
// 128x128 tile, BK=64, LDS 2x32KB, raw s_barrier + s_waitcnt vmcnt(8).
// EPI: 0 bf16; 2 relu(acc+biasN)->bf16; 4 (acc+biasN)->bf16.
// ---------------------------------------------------------------------------
template <int EPI, bool XCDSWZ>
__global__ __launch_bounds__(256)
void mgemm128c(const unsigned short* __restrict__ A, const unsigned short* __restrict__ B,
               unsigned short* __restrict__ C0, int K, int lda, int ldb, int ldc,
               long aOuter, long aInner, long bOuter, long bInner,
               long cOuter, long cInner, int nInner, int mValid,
               const float* __restrict__ biasN) {
    int bx = blockIdx.x, by = blockIdx.y;
    if (XCDSWZ) {
        int nwg = gridDim.x * gridDim.y;
        int flat = by * gridDim.x + bx;
        int cpx = nwg >> 3;
        int swz = (flat & 7) * cpx + (flat >> 3);
        bx = swz % gridDim.x; by = swz / gridDim.x;
    }
    int bz = blockIdx.z;
    int bo = bz / nInner, bi = bz - bo * nInner;
    const unsigned short* Ab = A + bo * aOuter + bi * aInner;
    const unsigned short* Bb = B + bo * bOuter + bi * bInner;

    __shared__ unsigned short As[2][128 * 64];
    __shared__ unsigned short Bs[2][128 * 64];

    int t = threadIdx.x;
    int m0 = by * 128, n0 = bx * 128;
    int lane = t & 63, wave = t >> 6;
    int wr = wave >> 1, wc = wave & 1;
    int la = lane & 15, hi = lane >> 4;

    f32x4 acc[4][4] = {};
    int rsub = t >> 3;
    int c8 = (t & 7) * 8;

    auto STAGE = [&](int buf, int k0) {
#pragma unroll
        for (int p = 0; p < 4; ++p) {
            int row = p * 32 + rsub;
            int ksw = k0 + KSWZ(row, c8);     // inverse-swizzled source
            gld_lds16(Ab + (long)(m0 + row) * lda + ksw, &As[buf][row * 64 + c8]);
            gld_lds16(Bb + (long)(n0 + row) * ldb + ksw, &Bs[buf][row * 64 + c8]);
        }
    };

    int ktiles = K >> 6;
    STAGE(0, 0);

    for (int kt = 0; kt < ktiles; ++kt) {
        int cur = kt & 1;
        if (kt + 1 < ktiles) {
            STAGE(cur ^ 1, (kt + 1) << 6);
            asm volatile("s_waitcnt vmcnt(8)" ::: "memory");   // prev tile landed
        } else {
            asm volatile("s_waitcnt vmcnt(0)" ::: "memory");
        }
        __builtin_amdgcn_s_barrier();          // buf[cur] ready for all
#pragma unroll
        for (int half = 0; half < 2; ++half) {
            int ko = half * 32 + hi * 8;
            bf16x8 a[4], b[4];
#pragma unroll
            for (int mi = 0; mi < 4; ++mi) {
                int ra = wr * 64 + mi * 16 + la;
                a[mi] = *(const bf16x8*)&As[cur][ra * 64 + KSWZ(ra, ko)];
            }
#pragma unroll
            for (int ni = 0; ni < 4; ++ni) {
                int rb = wc * 64 + ni * 16 + la;
                b[ni] = *(const bf16x8*)&Bs[cur][rb * 64 + KSWZ(rb, ko)];
            }
            __builtin_amdgcn_s_setprio(1);
#pragma unroll
            for (int mi = 0; mi < 4; ++mi)
#pragma unroll
                for (int ni = 0; ni < 4; ++ni)
                    acc[mi][ni] = __builtin_amdgcn_mfma_f32_16x16x32_bf16(a[mi], b[ni], acc[mi][ni], 0, 0, 0);
            __builtin_amdgcn_s_setprio(0);
        }
        __builtin_amdgcn_s_barrier();          // all reads of buf[cur] done
    }

    unsigned short* Ch = C0 + bo * cOuter + bi * cInner;
#pragma unroll
    for (int mi = 0; mi < 4; ++mi) {
#pragma unroll
        for (int ni = 0; ni < 4; ++ni) {
            int gn = n0 + wc * 64 + ni * 16 + la;
            int gmB = m0 + wr * 64 + mi * 16 + hi * 4;
            float bN = 0.f;
            if (EPI == 2 || EPI == 4) bN = biasN[gn];
#pragma unroll
            for (int rr = 0; rr < 4; ++rr) {
                int gm = gmB + rr;
                if (gm >= mValid) continue;
                float v = acc[mi][ni][rr];
                if (EPI == 0) Ch[(long)gm * ldc + gn] = f2bf(v);
                else if (EPI == 2) Ch[(long)gm * ldc + gn] = f2bf(fmaxf(v + bN, 0.f));
                else Ch[(long)gm * ldc + gn] = f2bf(v + bN);
            }
        }
    }
}

// ---------------------------------------------------------------------------
// cross-spectrum * complex weight, IN PLACE on QF. (bh, d, 256) layout.
// ---------------------------------------------------------------------------
__global__ void crossspec(unsigned short* __restrict__ QF, const unsigned short* __restrict__ KF,
                          const float* __restrict__ cw) {
    long idx = (long)blockIdx.x * 256 + threadIdx.x;
    if (idx >= (long)BATCH * NH * DK * NF) return;
    int f = (int)(idx % NF);
    long tq = idx / NF;
    int d = (int)(tq % DK);
    int bh = (int)(tq / DK);
    int h = bh & (NH - 1);
    long base = (long)bh * DK * PD + (long)d * PD;
    float qr = bf2f(QF[base + f]), qi = bf2f(QF[base + NF + f]);
    float kr = bf2f(KF[base + f]), ki = bf2f(KF[base + NF + f]);
    float cr = qr * kr + qi * ki;
    float ci = qi * kr - qr * ki;
    long wb = (((long)h * NF + f) * DK + d) * 2;
    float wr = cw[wb], wi = cw[wb + 1];
    QF[base + f]      = f2bf(cr * wr - ci * wi);
    QF[base + NF + f] = f2bf(cr * wi + ci * wr);
    if (f < PD - NF2) QF[base + NF2 + f] = 0;
}

// ---------------------------------------------------------------------------
// softmax over contiguous s (cols 0..199 of 256), bf16 in -> bf16 out
// ---------------------------------------------------------------------------
__global__ __launch_bounds__(256) void softmax_rows(const unsigned short* __restrict__ in,
                                                    unsigned short* __restrict__ out) {
    long row = (long)blockIdx.x * 4 + (threadIdx.x >> 6);
    int lane = threadIdx.x & 63;
    const unsigned short* p = in + row * PD;
    float v[4];
    float m = -1e30f;
#pragma unroll
    for (int i = 0; i < 4; ++i) {
        int s = lane + 64 * i;
        v[i] = (s < SEQ) ? bf2f(p[s]) : -1e30f;
        m = fmaxf(m, v[i]);
    }
#pragma unroll
    for (int o = 32; o; o >>= 1) m = fmaxf(m, __shfl_xor(m, o));
    float e[4], sum = 0.f;
#pragma unroll
    for (int i = 0; i < 4; ++i) {
        int s = lane + 64 * i;
        e[i] = (s < SEQ) ? expf(v[i] - m) : 0.f;
        sum += e[i];
    }
#pragma unroll
    for (int o = 32; o; o >>= 1) sum += __shfl_xor(sum, o);
    float inv = 1.f / sum;
    unsigned short* q = out + row * PD;
#pragma unroll
    for (int i = 0; i < 4; ++i) {
        int s = lane + 64 * i;
        q[s] = (s < SEQ) ? f2bf(e[i] * inv) : (unsigned short)0;
    }
}

// ---------------------------------------------------------------------------
// gelu(erf) + TF LayerNorm per 1024-wide row (bf16 in, fp32 out)
// ---------------------------------------------------------------------------
__global__ __launch_bounds__(256) void gelu_ln_kernel(const unsigned short* __restrict__ y2,
                               const float* __restrict__ lnw, const float* __restrict__ lnb,
                               float* __restrict__ out) {
    long row = blockIdx.x;
    int tid = threadIdx.x;
    const short4* xr = reinterpret_cast<const short4*>(y2 + row * HID);
    short4 h4 = xr[tid];
    float g[4];
    {
        float x0 = bf2f((unsigned short)h4.x), x1 = bf2f((unsigned short)h4.y);
        float x2 = bf2f((unsigned short)h4.z), x3 = bf2f((unsigned short)h4.w);
        g[0] = 0.5f * x0 * (1.f + erff(x0 * 0.70710678118654752f));
        g[1] = 0.5f * x1 * (1.f + erff(x1 * 0.70710678118654752f));
        g[2] = 0.5f * x2 * (1.f + erff(x2 * 0.70710678118654752f));
        g[3] = 0.5f * x3 * (1.f + erff(x3 * 0.70710678118654752f));
    }

    __shared__ float red[4];
    float s = g[0] + g[1] + g[2] + g[3];
#pragma unroll
    for (int o = 32; o > 0; o >>= 1) s += __shfl_down(s, o);
    if ((tid & 63) == 0) red[tid >> 6] = s;
    __syncthreads();
    float mean = (red[0] + red[1] + red[2] + red[3]) * (1.f / (float)HID);

    float v2 = 0.f;
#pragma unroll
    for (int p = 0; p < 4; ++p) { float d = g[p] - mean; v2 += d * d; }
    __syncthreads();
#pragma unroll
    for (int o = 32; o > 0; o >>= 1) v2 += __shfl_down(v2, o);
    if ((tid & 63) == 0) red[tid >> 6] = v2;
    __syncthreads();
    float var = (red[0] + red[1] + red[2] + red[3]) * (1.f / (float)HID);
    float rstd = rsqrtf(var + 1e-12f);

    float4 o4;
    int i0 = tid * 4;
    o4.x = (g[0] - mean) * rstd * lnw[i0 + 0] + lnb[i0 + 0];
    o4.y = (g[1] - mean) * rstd * lnw[i0 + 1] + lnb[i0 + 1];
    o4.z = (g[2] - mean) * rstd * lnw[i0 + 2] + lnb[i0 + 2];
    o4.w = (g[3] - mean) * rstd * lnw[i0 + 3] + lnb[i0 + 3];
    reinterpret_cast<float4*>(out + row * HID)[tid] = o4;
}

// ---------------------------------------------------------------------------
extern "C" void kernel_launch(void* const* d_in, const int* in_sizes, int n_in,
                              void* d_out, int out_size, void* d_ws, size_t ws_size,
                              hipStream_t stream) {
    const float* query = (const float*)d_in[0];
    const float* key   = (const float*)d_in[1];
    const float* value = (const float*)d_in[2];
    const float* w0 = (const float*)d_in[3];
    const float* w1 = (const float*)d_in[4];
    const float* w2 = (const float*)d_in[5];
    const float* w3 = (const float*)d_in[6];
    const float* attn_bias = (const float*)d_in[7];
    const float* cw = (const float*)d_in[8];
    const float* lw = (const float*)d_in[9];
    const float* lb = (const float*)d_in[10];
    const float* lnw = (const float*)d_in[11];
    const float* lnb = (const float*)d_in[12];
    float* out = (float*)d_out;

    char* base = (char*)d_ws;
    const long BH = (long)BATCH * NH;
    const long SZR = (long)BH * PD * PD;          // elements per 64MiB bf16 region
    const size_t M64 = 67108864;

    unsigned short* F_stack = (unsigned short*)(base + 0);
    unsigned short* G_stack = (unsigned short*)(base + 131072);
    unsigned short* w0T = (unsigned short*)(base + 262144);
    unsigned short* w1T = (unsigned short*)(base + 393216);
    unsigned short* w2T = (unsigned short*)(base + 524288);
    unsigned short* w3b = (unsigned short*)(base + 655360);
    unsigned short* lwb = (unsigned short*)(base + 786432);   // 2MiB
    char* rA = base + 4194304;            // qpT -> corr
    char* rB = rA + M64;                  // kpT -> probs
    char* rC = rB + M64;                  // vpT
    char* rD = rC + M64;                  // QF/R -> alphaT(bf16) -> y2(bf16)
    char* rE = rD + M64;                  // KF   -> X

    unsigned short* qpT = (unsigned short*)rA;
    unsigned short* kpT = (unsigned short*)rB;
    unsigned short* vpT = (unsigned short*)rC;
    unsigned short* QF  = (unsigned short*)rD;
    unsigned short* KF  = (unsigned short*)rE;
    unsigned short* corr = (unsigned short*)rA;
    unsigned short* alphaT = (unsigned short*)rD;
    unsigned short* probs = (unsigned short*)rB;
    unsigned short* X  = (unsigned short*)rE;
    unsigned short* y2 = (unsigned short*)rD;

    // tables + weight conversion
    init_tables_bf16<<<256, 256, 0, stream>>>(F_stack, G_stack);
    wtrans256<<<256, 256, 0, stream>>>(w0, w0T);
    wtrans256<<<256, 256, 0, stream>>>(w1, w1T);
    wtrans256<<<256, 256, 0, stream>>>(w2, w2T);
    w3pad<<<256, 256, 0, stream>>>(w3, w3b);
    fconv<<<(HID * HID + 255) / 256, 256, 0, stream>>>(lw, lwb, HID * HID);

    // projections: qpT[bh](d,s) = w0T @ q^T ; B = raw fp32 rows (s<200 valid)
    dim3 gproj(2, 2, BH);
    mgemm128<<<gproj, 256, 0, stream>>>(w0T, query, qpT, DK, DK, HID, PD,
        0L, 0L, (long)SEQ * HID, (long)DK, (long)NH * PD * PD, (long)PD * PD, NH, SEQ);
    mgemm128<<<gproj, 256, 0, stream>>>(w1T, key, kpT, DK, DK, HID, PD,
        0L, 0L, (long)SEQ * HID, (long)DK, (long)NH * PD * PD, (long)PD * PD, NH, SEQ);
    mgemm128<<<gproj, 256, 0, stream>>>(w2T, value, vpT, DK, DK, HID, PD,
        0L, 0L, (long)SEQ * HID, (long)DK, (long)NH * PD * PD, (long)PD * PD, NH, SEQ);

    // forward DFT (q and k batched via bo): QF[bh](d,f) = qpT @ F^T
    dim3 gfwd(2, 2, 2 * BH);
    mgemm128c<0, false><<<gfwd, 256, 0, stream>>>(qpT, F_stack, QF, PD, PD, PD, PD,
        SZR, (long)PD * PD, 0L, 0L, SZR, (long)PD * PD, (int)BH, PD, nullptr);

    // cross-spectrum * weight (in place on QF)
    long ncs = (long)BH * DK * NF;
    crossspec<<<(unsigned)((ncs + 255) / 256), 256, 0, stream>>>(QF, KF, cw);

    // inverse DFT: corr[bh](s,d) = G @ R^T, epilogue relu(+attn_bias over d)
    dim3 gstd(2, 2, BH);
    mgemm128c<2, false><<<gstd, 256, 0, stream>>>(G_stack, QF, corr, PD, PD, PD, PD,
        0L, 0L, (long)PD * PD, 0L, (long)PD * PD, 0L, 1, PD, attn_bias);

    // alphaT[bh](l,s) = w3b @ corr^T-form (bf16 out)
    mgemm128c<0, false><<<gstd, 256, 0, stream>>>(w3b, corr, alphaT, PD, PD, PD, PD,
        0L, 0L, (long)PD * PD, 0L, (long)PD * PD, 0L, 1, PD, nullptr);

    // softmax over contiguous s
    softmax_rows<<<(unsigned)(BH * PD / 4), 256, 0, stream>>>(alphaT, probs);

    // X[b, l, h*256+d] = probs(l,s) @ vpT(d,s)^T  -- direct, no transpose
    mgemm128c<0, false><<<gstd, 256, 0, stream>>>(probs, vpT, X, PD, PD, PD, HID,
        (long)NH * PD * PD, (long)PD * PD,
        (long)NH * PD * PD, (long)PD * PD,
        (long)LS * HID, (long)DK, NH, LS, nullptr);

    // y2 = X @ lw^T + lb : 25600 x 1024 x 1024  (bf16 out, XCD swizzle)
    dim3 glin(HID / 128, (BATCH * LS) / 128, 1);
    mgemm128c<4, true><<<glin, 256, 0, stream>>>(X, lwb, y2, HID, HID, HID, HID,
        0L, 0L, 0L, 0L, 0L, 0L, 1, BATCH * LS, lb);

    // gelu + LayerNorm
    gelu_ln_kernel<<<(unsigned)(BATCH * LS), 256, 0, stream>>>(y2, lnw, lnb, out);
}

// Round 7
// 615.516 us; speedup vs baseline: 1.2029x; 1.1382x over previous
//
#include <hip/hip_runtime.h>
#include <hip/hip_bf16.h>
#include <math.h>

#define BATCH 128
#define SEQ   200
#define HID   1024
#define NH    4
#define DK    256
#define NF    101    // SEQ/2+1
#define NF2   202    // stacked real+imag rows
#define LS    200
#define PD    256    // padded s / fidx / l dimension

typedef __attribute__((ext_vector_type(8))) short bf16x8;
typedef __attribute__((ext_vector_type(4))) float f32x4;

__device__ __forceinline__ unsigned short f2bf(float f) {
    union { float f; unsigned u; } v; v.f = f;
    unsigned r = v.u + 0x7fff + ((v.u >> 16) & 1);
    return (unsigned short)(r >> 16);
}
__device__ __forceinline__ float bf2f(unsigned short h) {
    union { unsigned u; float f; } v; v.u = ((unsigned)h) << 16;
    return v.f;
}

__device__ __forceinline__ void gld_lds16(const void* g, void* l) {
    __builtin_amdgcn_global_load_lds(
        (const __attribute__((address_space(1))) unsigned*)g,
        (__attribute__((address_space(3))) unsigned*)l, 16, 0, 0);
}

// T2 swizzle (16B granularity, involution): LDS slot (row,c8) holds global
// k-offset (c8 ^ ((row&7)<<3)). Balanced 8-slot spread -> bank-conflict-free
// b128 reads (verified round 5: SQ_LDS_BANK_CONFLICT -> 0).
#define KSWZ(row, c8) ((c8) ^ (((row) & 7) << 3))

// ---------------------------------------------------------------------------
// Tables, padded to 256x256, pad = 0 (round-2 derivation).
// ---------------------------------------------------------------------------
__global__ void init_tables_bf16(unsigned short* __restrict__ F, unsigned short* __restrict__ G) {
    int idx = blockIdx.x * 256 + threadIdx.x;
    const double inv = 0.07071067811865475244;
    const double PI2 = 6.283185307179586476925;
    {
        int fidx = idx >> 8, s = idx & 255;
        double v = 0.0;
        if (s < SEQ && fidx < NF2) {
            int f = (fidx < NF) ? fidx : fidx - NF;
            double ang = PI2 * (double)((f * s) % SEQ) / (double)SEQ;
            v = (fidx < NF) ? cos(ang) * inv : -sin(ang) * inv;
        }
        F[idx] = f2bf((float)v);
    }
    {
        int s = idx >> 8, j = idx & 255;
        double v = 0.0;
        if (s < SEQ && j < NF2) {
            if (j < NF) {
                double al = (j == 0 || j == NF - 1) ? 1.0 : 2.0;
                v = al * cos(PI2 * (double)((j * s) % SEQ) / (double)SEQ) * inv;
            } else {
                int f = j - NF;
                if (f != 0 && f != NF - 1)
                    v = -2.0 * sin(PI2 * (double)((f * s) % SEQ) / (double)SEQ) * inv;
            }
        }
        G[idx] = f2bf((float)v);
    }
}

__global__ void wtrans256(const float* __restrict__ src, unsigned short* __restrict__ dst) {
    int dout = blockIdx.x, din = threadIdx.x;
    dst[dout * 256 + din] = f2bf(src[din * 256 + dout]);
}

__global__ void w3pad(const float* __restrict__ src, unsigned short* __restrict__ dst) {
    int row = blockIdx.x, col = threadIdx.x;
    dst[row * 256 + col] = (row < LS) ? f2bf(src[row * 256 + col]) : (unsigned short)0;
}

__global__ void fconv(const float* __restrict__ src, unsigned short* __restrict__ dst, int n) {
    int i = blockIdx.x * 256 + threadIdx.x;
    if (i < n) dst[i] = f2bf(src[i]);
}

// ---------------------------------------------------------------------------
// Proj GEMM (B = fp32 reg-staged with convert). 128x128, BK=64,
// single-buffer 32KB LDS, swizzled (unchanged from round 6).
// ---------------------------------------------------------------------------
__global__ __launch_bounds__(256)
void mgemm128(const unsigned short* __restrict__ A, const float* __restrict__ Bf0,
              unsigned short* __restrict__ C0,
              int K, int lda, int ldb, int ldc,
              long aOuter, long aInner, long bOuter, long bInner,
              long cOuter, long cInner, int nInner, int nbValid) {
    int bz = blockIdx.z;
    int bo = bz / nInner, bi = bz - bo * nInner;
    const unsigned short* Ab = A + bo * aOuter + bi * aInner;
    const float* Bf = Bf0 + bo * bOuter + bi * bInner;

    __shared__ unsigned short As[128 * 64];
    __shared__ unsigned short Bs[128 * 64];

    int t = threadIdx.x;
    int m0 = blockIdx.y * 128, n0 = blockIdx.x * 128;
    int lane = t & 63, wave = t >> 6;
    int wr = wave >> 1, wc = wave & 1;
    int la = lane & 15, hi = lane >> 4;

    f32x4 acc[4][4] = {};
    int rsub = t >> 3;
    int c8 = (t & 7) * 8;

    for (int k0 = 0; k0 < K; k0 += 64) {
#pragma unroll
        for (int p = 0; p < 4; ++p) {
            int row = p * 32 + rsub;
            gld_lds16(Ab + (long)(m0 + row) * lda + k0 + KSWZ(row, c8), &As[row * 64 + c8]);
        }
#pragma unroll
        for (int p = 0; p < 4; ++p) {
            int row = p * 32 + rsub;
            int gn = n0 + row;
            unsigned short tmp[8];
            if (gn < nbValid) {
                const float4* src = reinterpret_cast<const float4*>(Bf + (long)gn * ldb + k0 + c8);
                float4 x0 = src[0], x1 = src[1];
                tmp[0] = f2bf(x0.x); tmp[1] = f2bf(x0.y); tmp[2] = f2bf(x0.z); tmp[3] = f2bf(x0.w);
                tmp[4] = f2bf(x1.x); tmp[5] = f2bf(x1.y); tmp[6] = f2bf(x1.z); tmp[7] = f2bf(x1.w);
            } else {
#pragma unroll
                for (int j = 0; j < 8; ++j) tmp[j] = 0;
            }
            *(bf16x8*)&Bs[row * 64 + KSWZ(row, c8)] = *(bf16x8*)tmp;
        }
        __syncthreads();
#pragma unroll
        for (int half = 0; half < 2; ++half) {
            int ko = half * 32 + hi * 8;
            bf16x8 a[4], b[4];
#pragma unroll
            for (int mi = 0; mi < 4; ++mi) {
                int ra = wr * 64 + mi * 16 + la;
                a[mi] = *(const bf16x8*)&As[ra * 64 + KSWZ(ra, ko)];
            }
#pragma unroll
            for (int ni = 0; ni < 4; ++ni) {
                int rb = wc * 64 + ni * 16 + la;
                b[ni] = *(const bf16x8*)&Bs[rb * 64 + KSWZ(rb, ko)];
            }
#pragma unroll
            for (int mi = 0; mi < 4; ++mi)
#pragma unroll
                for (int ni = 0; ni < 4; ++ni)
                    acc[mi][ni] = __builtin_amdgcn_mfma_f32_16x16x32_bf16(a[mi], b[ni], acc[mi][ni], 0, 0, 0);
        }
        __syncthreads();
    }

    unsigned short* Ch = C0 + bo * cOuter + bi * cInner;
#pragma unroll
    for (int mi = 0; mi < 4; ++mi) {
#pragma unroll
        for (int ni = 0; ni < 4; ++ni) {
            int gn = n0 + wc * 64 + ni * 16 + la;
            int gmB = m0 + wr * 64 + mi * 16 + hi * 4;
#pragma unroll
            for (int rr = 0; rr < 4; ++rr)
                Ch[(long)(gmB + rr) * ldc + gn] = f2bf(acc[mi][ni][rr]);
        }
    }
}

// ---------------------------------------------------------------------------
// 256x256-tile bf16 MFMA GEMM (m201 geometry): BK=64, 8 waves (2Mx4N, each
// owning a 128x64 output), 128KB dynamic-LDS double buffer, counted-vmcnt
// depth-1 prefetch (never vmcnt(0) mid-loop), T2 swizzle, setprio on MFMA.
// Ledger: STAGE kt+1 into buf^1 (freed by barrier ending kt-1); vmcnt(8)
// waits only tile kt's own 8 gld_lds; barrier; 24 ds_read + 64 MFMA (~2000cy
// MFMA per K-tile hides the prefetch latency); barrier.
// EPI: 0 bf16; 2 relu(acc+biasN)->bf16; 4 (acc+biasN)->bf16.
// ---------------------------------------------------------------------------
template <int EPI, bool XCDSWZ>
__global__ __launch_bounds__(512, 2)
void mgemm256(const unsigned short* __restrict__ A, const unsigned short* __restrict__ B,
              unsigned short* __restrict__ C0, int K, int lda, int ldb, int ldc,
              long aOuter, long aInner, long bOuter, long bInner,
              long cOuter, long cInner, int nInner, int mValid,
              const float* __restrict__ biasN) {
    extern __shared__ unsigned short lds[];   // 65536 elems = 128KB
    unsigned short* AsB = lds;                // 2 x 16384
    unsigned short* BsB = lds + 32768;        // 2 x 16384

    int bx = blockIdx.x, by = blockIdx.y;
    if (XCDSWZ) {
        int nwg = gridDim.x * gridDim.y;      // must be %8==0 at call site
        int flat = by * gridDim.x + bx;
        int cpx = nwg >> 3;
        int swz = (flat & 7) * cpx + (flat >> 3);
        bx = swz % gridDim.x; by = swz / gridDim.x;
    }
    int bz = blockIdx.z;
    int bo = bz / nInner, bi = bz - bo * nInner;
    const unsigned short* Ab = A + bo * aOuter + bi * aInner;
    const unsigned short* Bb = B + bo * bOuter + bi * bInner;

    int t = threadIdx.x;
    int m0 = by * 256, n0 = bx * 256;
    int lane = t & 63, wave = t >> 6;
    int wr = wave >> 2, wc = wave & 3;        // 2 x 4 wave grid
    int la = lane & 15, hi = lane >> 4;

    f32x4 acc[8][4] = {};                     // 128 VGPR
    int rsub = t >> 3;                        // 0..63
    int c8 = (t & 7) * 8;

    // one STAGE = 8 gld_lds per thread (4 A rows-slabs + 4 B), LDS dest is
    // linear (base + t*16B within each slab) as gld_lds requires.
    auto STAGE = [&](int buf, int kt) {
        int k0 = kt << 6;
        unsigned short* Asb = AsB + buf * 16384;
        unsigned short* Bsb = BsB + buf * 16384;
#pragma unroll
        for (int p = 0; p < 4; ++p) {
            int row = p * 64 + rsub;
            int ksw = k0 + KSWZ(row, c8);
            gld_lds16(Ab + (long)(m0 + row) * lda + ksw, &Asb[row * 64 + c8]);
            gld_lds16(Bb + (long)(n0 + row) * ldb + ksw, &Bsb[row * 64 + c8]);
        }
    };

    int nkt = K >> 6;
    STAGE(0, 0);

    for (int kt = 0; kt < nkt; ++kt) {
        int cur = kt & 1;
        if (kt + 1 < nkt) {
            STAGE(cur ^ 1, kt + 1);
            asm volatile("s_waitcnt vmcnt(8)" ::: "memory");   // tile kt landed
        } else {
            asm volatile("s_waitcnt vmcnt(0)" ::: "memory");
        }
        __builtin_amdgcn_s_barrier();
        const unsigned short* Acur = AsB + cur * 16384;
        const unsigned short* Bcur = BsB + cur * 16384;
#pragma unroll
        for (int half = 0; half < 2; ++half) {
            int ko = half * 32 + hi * 8;
            bf16x8 a[8], b[4];
#pragma unroll
            for (int mi = 0; mi < 8; ++mi) {
                int ra = wr * 128 + mi * 16 + la;
                a[mi] = *(const bf16x8*)&Acur[ra * 64 + KSWZ(ra, ko)];
            }
#pragma unroll
            for (int ni = 0; ni < 4; ++ni) {
                int rb = wc * 64 + ni * 16 + la;
                b[ni] = *(const bf16x8*)&Bcur[rb * 64 + KSWZ(rb, ko)];
            }
            __builtin_amdgcn_s_setprio(1);
#pragma unroll
            for (int mi = 0; mi < 8; ++mi)
#pragma unroll
                for (int ni = 0; ni < 4; ++ni)
                    acc[mi][ni] = __builtin_amdgcn_mfma_f32_16x16x32_bf16(a[mi], b[ni], acc[mi][ni], 0, 0, 0);
            __builtin_amdgcn_s_setprio(0);
        }
        __builtin_amdgcn_s_barrier();
    }

    unsigned short* Ch = C0 + bo * cOuter + bi * cInner;
#pragma unroll
    for (int mi = 0; mi < 8; ++mi) {
#pragma unroll
        for (int ni = 0; ni < 4; ++ni) {
            int gn = n0 + wc * 64 + ni * 16 + la;
            int gmB = m0 + wr * 128 + mi * 16 + hi * 4;
            float bN = 0.f;
            if (EPI == 2 || EPI == 4) bN = biasN[gn];
#pragma unroll
            for (int rr = 0; rr < 4; ++rr) {
                int gm = gmB + rr;
                if (gm >= mValid) continue;
                float v = acc[mi][ni][rr];
                if (EPI == 0) Ch[(long)gm * ldc + gn] = f2bf(v);
                else if (EPI == 2) Ch[(long)gm * ldc + gn] = f2bf(fmaxf(v + bN, 0.f));
                else Ch[(long)gm * ldc + gn] = f2bf(v + bN);
            }
        }
    }
}

// ---------------------------------------------------------------------------
// cross-spectrum * complex weight, IN PLACE on QF. (bh, d, 256) layout.
// ---------------------------------------------------------------------------
__global__ void crossspec(unsigned short* __restrict__ QF, const unsigned short* __restrict__ KF,
                          const float* __restrict__ cw) {
    long idx = (long)blockIdx.x * 256 + threadIdx.x;
    if (idx >= (long)BATCH * NH * DK * NF) return;
    int f = (int)(idx % NF);
    long tq = idx / NF;
    int d = (int)(tq % DK);
    int bh = (int)(tq / DK);
    int h = bh & (NH - 1);
    long base = (long)bh * DK * PD + (long)d * PD;
    float qr = bf2f(QF[base + f]), qi = bf2f(QF[base + NF + f]);
    float kr = bf2f(KF[base + f]), ki = bf2f(KF[base + NF + f]);
    float cr = qr * kr + qi * ki;
    float ci = qi * kr - qr * ki;
    long wb = (((long)h * NF + f) * DK + d) * 2;
    float wr = cw[wb], wi = cw[wb + 1];
    QF[base + f]      = f2bf(cr * wr - ci * wi);
    QF[base + NF + f] = f2bf(cr * wi + ci * wr);
    if (f < PD - NF2) QF[base + NF2 + f] = 0;
}

// ---------------------------------------------------------------------------
// softmax over contiguous s (cols 0..199 of 256), bf16 in -> bf16 out
// ---------------------------------------------------------------------------
__global__ __launch_bounds__(256) void softmax_rows(const unsigned short* __restrict__ in,
                                                    unsigned short* __restrict__ out) {
    long row = (long)blockIdx.x * 4 + (threadIdx.x >> 6);
    int lane = threadIdx.x & 63;
    const unsigned short* p = in + row * PD;
    float v[4];
    float m = -1e30f;
#pragma unroll
    for (int i = 0; i < 4; ++i) {
        int s = lane + 64 * i;
        v[i] = (s < SEQ) ? bf2f(p[s]) : -1e30f;
        m = fmaxf(m, v[i]);
    }
#pragma unroll
    for (int o = 32; o; o >>= 1) m = fmaxf(m, __shfl_xor(m, o));
    float e[4], sum = 0.f;
#pragma unroll
    for (int i = 0; i < 4; ++i) {
        int s = lane + 64 * i;
        e[i] = (s < SEQ) ? expf(v[i] - m) : 0.f;
        sum += e[i];
    }
#pragma unroll
    for (int o = 32; o; o >>= 1) sum += __shfl_xor(sum, o);
    float inv = 1.f / sum;
    unsigned short* q = out + row * PD;
#pragma unroll
    for (int i = 0; i < 4; ++i) {
        int s = lane + 64 * i;
        q[s] = (s < SEQ) ? f2bf(e[i] * inv) : (unsigned short)0;
    }
}

// ---------------------------------------------------------------------------
// gelu(erf) + TF LayerNorm per 1024-wide row (bf16 in, fp32 out)
// ---------------------------------------------------------------------------
__global__ __launch_bounds__(256) void gelu_ln_kernel(const unsigned short* __restrict__ y2,
                               const float* __restrict__ lnw, const float* __restrict__ lnb,
                               float* __restrict__ out) {
    long row = blockIdx.x;
    int tid = threadIdx.x;
    const short4* xr = reinterpret_cast<const short4*>(y2 + row * HID);
    short4 h4 = xr[tid];
    float g[4];
    {
        float x0 = bf2f((unsigned short)h4.x), x1 = bf2f((unsigned short)h4.y);
        float x2 = bf2f((unsigned short)h4.z), x3 = bf2f((unsigned short)h4.w);
        g[0] = 0.5f * x0 * (1.f + erff(x0 * 0.70710678118654752f));
        g[1] = 0.5f * x1 * (1.f + erff(x1 * 0.70710678118654752f));
        g[2] = 0.5f * x2 * (1.f + erff(x2 * 0.70710678118654752f));
        g[3] = 0.5f * x3 * (1.f + erff(x3 * 0.70710678118654752f));
    }

    __shared__ float red[4];
    float s = g[0] + g[1] + g[2] + g[3];
#pragma unroll
    for (int o = 32; o > 0; o >>= 1) s += __shfl_down(s, o);
    if ((tid & 63) == 0) red[tid >> 6] = s;
    __syncthreads();
    float mean = (red[0] + red[1] + red[2] + red[3]) * (1.f / (float)HID);

    float v2 = 0.f;
#pragma unroll
    for (int p = 0; p < 4; ++p) { float d = g[p] - mean; v2 += d * d; }
    __syncthreads();
#pragma unroll
    for (int o = 32; o > 0; o >>= 1) v2 += __shfl_down(v2, o);
    if ((tid & 63) == 0) red[tid >> 6] = v2;
    __syncthreads();
    float var = (red[0] + red[1] + red[2] + red[3]) * (1.f / (float)HID);
    float rstd = rsqrtf(var + 1e-12f);

    float4 o4;
    int i0 = tid * 4;
    o4.x = (g[0] - mean) * rstd * lnw[i0 + 0] + lnb[i0 + 0];
    o4.y = (g[1] - mean) * rstd * lnw[i0 + 1] + lnb[i0 + 1];
    o4.z = (g[2] - mean) * rstd * lnw[i0 + 2] + lnb[i0 + 2];
    o4.w = (g[3] - mean) * rstd * lnw[i0 + 3] + lnb[i0 + 3];
    reinterpret_cast<float4*>(out + row * HID)[tid] = o4;
}

// ---------------------------------------------------------------------------
extern "C" void kernel_launch(void* const* d_in, const int* in_sizes, int n_in,
                              void* d_out, int out_size, void* d_ws, size_t ws_size,
                              hipStream_t stream) {
    const float* query = (const float*)d_in[0];
    const float* key   = (const float*)d_in[1];
    const float* value = (const float*)d_in[2];
    const float* w0 = (const float*)d_in[3];
    const float* w1 = (const float*)d_in[4];
    const float* w2 = (const float*)d_in[5];
    const float* w3 = (const float*)d_in[6];
    const float* attn_bias = (const float*)d_in[7];
    const float* cw = (const float*)d_in[8];
    const float* lw = (const float*)d_in[9];
    const float* lb = (const float*)d_in[10];
    const float* lnw = (const float*)d_in[11];
    const float* lnb = (const float*)d_in[12];
    float* out = (float*)d_out;

    char* base = (char*)d_ws;
    const long BH = (long)BATCH * NH;
    const long SZR = (long)BH * PD * PD;          // elements per 64MiB bf16 region
    const size_t M64 = 67108864;

    unsigned short* F_stack = (unsigned short*)(base + 0);
    unsigned short* G_stack = (unsigned short*)(base + 131072);
    unsigned short* w0T = (unsigned short*)(base + 262144);
    unsigned short* w1T = (unsigned short*)(base + 393216);
    unsigned short* w2T = (unsigned short*)(base + 524288);
    unsigned short* w3b = (unsigned short*)(base + 655360);
    unsigned short* lwb = (unsigned short*)(base + 786432);   // 2MiB
    char* rA = base + 4194304;            // qpT -> corr
    char* rB = rA + M64;                  // kpT -> probs
    char* rC = rB + M64;                  // vpT
    char* rD = rC + M64;                  // QF/R -> alphaT(bf16) -> y2(bf16)
    char* rE = rD + M64;                  // KF   -> X

    unsigned short* qpT = (unsigned short*)rA;
    unsigned short* kpT = (unsigned short*)rB;
    unsigned short* vpT = (unsigned short*)rC;
    unsigned short* QF  = (unsigned short*)rD;
    unsigned short* KF  = (unsigned short*)rE;
    unsigned short* corr = (unsigned short*)rA;
    unsigned short* alphaT = (unsigned short*)rD;
    unsigned short* probs = (unsigned short*)rB;
    unsigned short* X  = (unsigned short*)rE;
    unsigned short* y2 = (unsigned short*)rD;

    const size_t LDS256 = 131072;   // 128KB dynamic LDS for mgemm256

    // tables + weight conversion
    init_tables_bf16<<<256, 256, 0, stream>>>(F_stack, G_stack);
    wtrans256<<<256, 256, 0, stream>>>(w0, w0T);
    wtrans256<<<256, 256, 0, stream>>>(w1, w1T);
    wtrans256<<<256, 256, 0, stream>>>(w2, w2T);
    w3pad<<<256, 256, 0, stream>>>(w3, w3b);
    fconv<<<(HID * HID + 255) / 256, 256, 0, stream>>>(lw, lwb, HID * HID);

    // projections: qpT[bh](d,s) = w0T @ q^T ; B = raw fp32 rows (s<200 valid)
    dim3 gproj(2, 2, BH);
    mgemm128<<<gproj, 256, 0, stream>>>(w0T, query, qpT, DK, DK, HID, PD,
        0L, 0L, (long)SEQ * HID, (long)DK, (long)NH * PD * PD, (long)PD * PD, NH, SEQ);
    mgemm128<<<gproj, 256, 0, stream>>>(w1T, key, kpT, DK, DK, HID, PD,
        0L, 0L, (long)SEQ * HID, (long)DK, (long)NH * PD * PD, (long)PD * PD, NH, SEQ);
    mgemm128<<<gproj, 256, 0, stream>>>(w2T, value, vpT, DK, DK, HID, PD,
        0L, 0L, (long)SEQ * HID, (long)DK, (long)NH * PD * PD, (long)PD * PD, NH, SEQ);

    // forward DFT (q and k batched via bo): QF[bh](d,f) = qpT @ F^T
    mgemm256<0, false><<<dim3(1, 1, 2 * BH), 512, LDS256, stream>>>(
        qpT, F_stack, QF, PD, PD, PD, PD,
        SZR, (long)PD * PD, 0L, 0L, SZR, (long)PD * PD, (int)BH, PD, nullptr);

    // cross-spectrum * weight (in place on QF)
    long ncs = (long)BH * DK * NF;
    crossspec<<<(unsigned)((ncs + 255) / 256), 256, 0, stream>>>(QF, KF, cw);

    // inverse DFT: corr[bh](s,d) = G @ R^T, epilogue relu(+attn_bias over d)
    mgemm256<2, false><<<dim3(1, 1, BH), 512, LDS256, stream>>>(
        G_stack, QF, corr, PD, PD, PD, PD,
        0L, 0L, (long)PD * PD, 0L, (long)PD * PD, 0L, 1, PD, attn_bias);

    // alphaT[bh](l,s) = w3b @ corr^T-form (bf16 out)
    mgemm256<0, false><<<dim3(1, 1, BH), 512, LDS256, stream>>>(
        w3b, corr, alphaT, PD, PD, PD, PD,
        0L, 0L, (long)PD * PD, 0L, (long)PD * PD, 0L, 1, PD, nullptr);

    // softmax over contiguous s
    softmax_rows<<<(unsigned)(BH * PD / 4), 256, 0, stream>>>(alphaT, probs);

    // X[b, l, h*256+d] = probs(l,s) @ vpT(d,s)^T  -- direct, no transpose
    mgemm256<0, false><<<dim3(1, 1, BH), 512, LDS256, stream>>>(
        probs, vpT, X, PD, PD, PD, HID,
        (long)NH * PD * PD, (long)PD * PD,
        (long)NH * PD * PD, (long)PD * PD,
        (long)LS * HID, (long)DK, NH, LS, nullptr);

    // y2 = X @ lw^T + lb : 25600 x 1024 x 1024  (bf16 out, XCD swizzle, 400 wg)
    mgemm256<4, true><<<dim3(HID / 256, (BATCH * LS) / 256, 1), 512, LDS256, stream>>>(
        X, lwb, y2, HID, HID, HID, HID,
        0L, 0L, 0L, 0L, 0L, 0L, 1, BATCH * LS, lb);

    // gelu + LayerNorm
    gelu_ln_kernel<<<(unsigned)(BATCH * LS), 256, 0, stream>>>(y2, lnw, lnb, out);
}

// Round 8
// 605.084 us; speedup vs baseline: 1.2236x; 1.0172x over previous
//
#include <hip/hip_runtime.h>
#include <hip/hip_bf16.h>
#include <math.h>

#define BATCH 128
#define SEQ   200
#define HID   1024
#define NH    4
#define DK    256
#define NF    101    // SEQ/2+1
#define NF2   202    // stacked real+imag rows
#define LS    200
#define PD    256    // padded s / fidx / l dimension

typedef __attribute__((ext_vector_type(8))) short bf16x8;
typedef __attribute__((ext_vector_type(4))) float f32x4;

__device__ __forceinline__ unsigned short f2bf(float f) {
    union { float f; unsigned u; } v; v.f = f;
    unsigned r = v.u + 0x7fff + ((v.u >> 16) & 1);
    return (unsigned short)(r >> 16);
}
__device__ __forceinline__ float bf2f(unsigned short h) {
    union { unsigned u; float f; } v; v.u = ((unsigned)h) << 16;
    return v.f;
}

__device__ __forceinline__ void gld_lds16(const void* g, void* l) {
    __builtin_amdgcn_global_load_lds(
        (const __attribute__((address_space(1))) unsigned*)g,
        (__attribute__((address_space(3))) unsigned*)l, 16, 0, 0);
}

// T2 swizzle (16B granularity, involution): LDS slot (row,c8) holds global
// k-offset (c8 ^ ((row&7)<<3)). Conflict-free b128 reads (round 5: 2e7 -> 0).
#define KSWZ(row, c8) ((c8) ^ (((row) & 7) << 3))

// ---------------------------------------------------------------------------
// Tables, padded to 256x256, pad = 0 (round-2 derivation).
// ---------------------------------------------------------------------------
__global__ void init_tables_bf16(unsigned short* __restrict__ F, unsigned short* __restrict__ G) {
    int idx = blockIdx.x * 256 + threadIdx.x;
    const double inv = 0.07071067811865475244;
    const double PI2 = 6.283185307179586476925;
    {
        int fidx = idx >> 8, s = idx & 255;
        double v = 0.0;
        if (s < SEQ && fidx < NF2) {
            int f = (fidx < NF) ? fidx : fidx - NF;
            double ang = PI2 * (double)((f * s) % SEQ) / (double)SEQ;
            v = (fidx < NF) ? cos(ang) * inv : -sin(ang) * inv;
        }
        F[idx] = f2bf((float)v);
    }
    {
        int s = idx >> 8, j = idx & 255;
        double v = 0.0;
        if (s < SEQ && j < NF2) {
            if (j < NF) {
                double al = (j == 0 || j == NF - 1) ? 1.0 : 2.0;
                v = al * cos(PI2 * (double)((j * s) % SEQ) / (double)SEQ) * inv;
            } else {
                int f = j - NF;
                if (f != 0 && f != NF - 1)
                    v = -2.0 * sin(PI2 * (double)((f * s) % SEQ) / (double)SEQ) * inv;
            }
        }
        G[idx] = f2bf((float)v);
    }
}

__global__ void wtrans256(const float* __restrict__ src, unsigned short* __restrict__ dst) {
    int dout = blockIdx.x, din = threadIdx.x;
    dst[dout * 256 + din] = f2bf(src[din * 256 + dout]);
}

__global__ void w3pad(const float* __restrict__ src, unsigned short* __restrict__ dst) {
    int row = blockIdx.x, col = threadIdx.x;
    dst[row * 256 + col] = (row < LS) ? f2bf(src[row * 256 + col]) : (unsigned short)0;
}

__global__ void fconv(const float* __restrict__ src, unsigned short* __restrict__ dst, int n) {
    int i = blockIdx.x * 256 + threadIdx.x;
    if (i < n) dst[i] = f2bf(src[i]);
}

// ---------------------------------------------------------------------------
// Proj GEMM (B = fp32 reg-staged with convert). 128x128, BK=64,
// single-buffer 32KB LDS, swizzled (unchanged from round 6).
// ---------------------------------------------------------------------------
__global__ __launch_bounds__(256)
void mgemm128(const unsigned short* __restrict__ A, const float* __restrict__ Bf0,
              unsigned short* __restrict__ C0,
              int K, int lda, int ldb, int ldc,
              long aOuter, long aInner, long bOuter, long bInner,
              long cOuter, long cInner, int nInner, int nbValid) {
    int bz = blockIdx.z;
    int bo = bz / nInner, bi = bz - bo * nInner;
    const unsigned short* Ab = A + bo * aOuter + bi * aInner;
    const float* Bf = Bf0 + bo * bOuter + bi * bInner;

    __shared__ unsigned short As[128 * 64];
    __shared__ unsigned short Bs[128 * 64];

    int t = threadIdx.x;
    int m0 = blockIdx.y * 128, n0 = blockIdx.x * 128;
    int lane = t & 63, wave = t >> 6;
    int wr = wave >> 1, wc = wave & 1;
    int la = lane & 15, hi = lane >> 4;

    f32x4 acc[4][4] = {};
    int rsub = t >> 3;
    int c8 = (t & 7) * 8;

    for (int k0 = 0; k0 < K; k0 += 64) {
#pragma unroll
        for (int p = 0; p < 4; ++p) {
            int row = p * 32 + rsub;
            gld_lds16(Ab + (long)(m0 + row) * lda + k0 + KSWZ(row, c8), &As[row * 64 + c8]);
        }
#pragma unroll
        for (int p = 0; p < 4; ++p) {
            int row = p * 32 + rsub;
            int gn = n0 + row;
            unsigned short tmp[8];
            if (gn < nbValid) {
                const float4* src = reinterpret_cast<const float4*>(Bf + (long)gn * ldb + k0 + c8);
                float4 x0 = src[0], x1 = src[1];
                tmp[0] = f2bf(x0.x); tmp[1] = f2bf(x0.y); tmp[2] = f2bf(x0.z); tmp[3] = f2bf(x0.w);
                tmp[4] = f2bf(x1.x); tmp[5] = f2bf(x1.y); tmp[6] = f2bf(x1.z); tmp[7] = f2bf(x1.w);
            } else {
#pragma unroll
                for (int j = 0; j < 8; ++j) tmp[j] = 0;
            }
            *(bf16x8*)&Bs[row * 64 + KSWZ(row, c8)] = *(bf16x8*)tmp;
        }
        __syncthreads();
#pragma unroll
        for (int half = 0; half < 2; ++half) {
            int ko = half * 32 + hi * 8;
            bf16x8 a[4], b[4];
#pragma unroll
            for (int mi = 0; mi < 4; ++mi) {
                int ra = wr * 64 + mi * 16 + la;
                a[mi] = *(const bf16x8*)&As[ra * 64 + KSWZ(ra, ko)];
            }
#pragma unroll
            for (int ni = 0; ni < 4; ++ni) {
                int rb = wc * 64 + ni * 16 + la;
                b[ni] = *(const bf16x8*)&Bs[rb * 64 + KSWZ(rb, ko)];
            }
#pragma unroll
            for (int mi = 0; mi < 4; ++mi)
#pragma unroll
                for (int ni = 0; ni < 4; ++ni)
                    acc[mi][ni] = __builtin_amdgcn_mfma_f32_16x16x32_bf16(a[mi], b[ni], acc[mi][ni], 0, 0, 0);
        }
        __syncthreads();
    }

    unsigned short* Ch = C0 + bo * cOuter + bi * cInner;
#pragma unroll
    for (int mi = 0; mi < 4; ++mi) {
#pragma unroll
        for (int ni = 0; ni < 4; ++ni) {
            int gn = n0 + wc * 64 + ni * 16 + la;
            int gmB = m0 + wr * 64 + mi * 16 + hi * 4;
#pragma unroll
            for (int rr = 0; rr < 4; ++rr)
                Ch[(long)(gmB + rr) * ldc + gn] = f2bf(acc[mi][ni][rr]);
        }
    }
}

// ---------------------------------------------------------------------------
// 256x256-tile bf16 MFMA GEMM with 4-phase-per-K-tile interleave (m201-style):
// BK=64, 8 waves (2Mx4N, each owns 128x64), 128KB dynamic-LDS double buffer.
// Per phase: issue one 16KB stage chunk of tile kt+1, ds_read one operand
// quadrant, setprio(1)+16 MFMA+setprio(0), s_barrier. Counted vmcnt ONCE per
// K-tile at phase 0: vmcnt(2) waits exactly tile kt's 8 loads (chunk just
// issued stays in flight). Ledger: tile kt fully staged during kt-1's phases;
// WAR on buf^1 guarded by phase-3 barrier; ds_read->MFMA deps are register
// deps (compiler lgkmcnt). sched_barrier(0) after the phase-0 barrier pins
// the first (correctness-critical) ds_reads below it.
// EPI: 0 bf16; 2 relu(acc+biasN)->bf16; 4 (acc+biasN)->bf16.
// ---------------------------------------------------------------------------
template <int EPI, bool XCDSWZ>
__global__ __launch_bounds__(512, 2)
void mgemm256(const unsigned short* __restrict__ A, const unsigned short* __restrict__ B,
              unsigned short* __restrict__ C0, int K, int lda, int ldb, int ldc,
              long aOuter, long aInner, long bOuter, long bInner,
              long cOuter, long cInner, int nInner, int mValid,
              const float* __restrict__ biasN) {
    extern __shared__ unsigned short lds[];   // 65536 elems = 128KB
    unsigned short* AsB = lds;                // 2 x 16384
    unsigned short* BsB = lds + 32768;        // 2 x 16384

    int bx = blockIdx.x, by = blockIdx.y;
    if (XCDSWZ) {
        int nwg = gridDim.x * gridDim.y;      // %8==0 at call site
        int flat = by * gridDim.x + bx;
        int cpx = nwg >> 3;
        int swz = (flat & 7) * cpx + (flat >> 3);
        bx = swz % gridDim.x; by = swz / gridDim.x;
    }
    int bz = blockIdx.z;
    int bo = bz / nInner, bi = bz - bo * nInner;
    const unsigned short* Ab = A + bo * aOuter + bi * aInner;
    const unsigned short* Bb = B + bo * bOuter + bi * bInner;

    int t = threadIdx.x;
    int m0 = by * 256, n0 = bx * 256;
    int lane = t & 63, wave = t >> 6;
    int wr = wave >> 2, wc = wave & 3;        // 2 x 4 wave grid
    int la = lane & 15, hi = lane >> 4;

    f32x4 acc[8][4] = {};                     // 128 VGPR
    int rsub = t >> 3;                        // 0..63
    int c8 = (t & 7) * 8;

    // stage one 16KB chunk: half h (rows h*128 .. h*128+127) of A or B
    auto stageA = [&](unsigned short* dst, long k0, int h) {
#pragma unroll
        for (int p = 0; p < 2; ++p) {
            int row = h * 128 + p * 64 + rsub;
            gld_lds16(Ab + (long)(m0 + row) * lda + k0 + KSWZ(row, c8), &dst[row * 64 + c8]);
        }
    };
    auto stageB = [&](unsigned short* dst, long k0, int h) {
#pragma unroll
        for (int p = 0; p < 2; ++p) {
            int row = h * 128 + p * 64 + rsub;
            gld_lds16(Bb + (long)(n0 + row) * ldb + k0 + KSWZ(row, c8), &dst[row * 64 + c8]);
        }
    };
    auto ldf = [&](const unsigned short* P, int row, int ko) -> bf16x8 {
        return *(const bf16x8*)&P[row * 64 + KSWZ(row, ko)];
    };

#define MFMA_ROW(mi, xa) \
    acc[mi][0] = __builtin_amdgcn_mfma_f32_16x16x32_bf16(xa, b0, acc[mi][0], 0, 0, 0); \
    acc[mi][1] = __builtin_amdgcn_mfma_f32_16x16x32_bf16(xa, b1, acc[mi][1], 0, 0, 0); \
    acc[mi][2] = __builtin_amdgcn_mfma_f32_16x16x32_bf16(xa, b2, acc[mi][2], 0, 0, 0); \
    acc[mi][3] = __builtin_amdgcn_mfma_f32_16x16x32_bf16(xa, b3, acc[mi][3], 0, 0, 0);

    int nkt = K >> 6;
    // prologue: full stage of tile 0 into buf 0
    stageA(AsB, 0, 0); stageA(AsB, 0, 1);
    stageB(BsB, 0, 0); stageB(BsB, 0, 1);

    for (int kt = 0; kt < nkt; ++kt) {
        int cur = kt & 1;
        const unsigned short* Ac = AsB + cur * 16384;
        const unsigned short* Bc = BsB + cur * 16384;
        unsigned short* An = AsB + (cur ^ 1) * 16384;
        unsigned short* Bn = BsB + (cur ^ 1) * 16384;
        bool pre = (kt + 1) < nkt;
        long kn = (long)(kt + 1) << 6;

        bf16x8 b0, b1, b2, b3;

        // -------- phase 0: stage A-h0(next); validate tile kt; k-half0, m0-3
        if (pre) {
            stageA(An, kn, 0);
            asm volatile("s_waitcnt vmcnt(2)" ::: "memory");  // kt's 8 landed
        } else {
            asm volatile("s_waitcnt vmcnt(0)" ::: "memory");
        }
        __builtin_amdgcn_s_barrier();
        __builtin_amdgcn_sched_barrier(0);
        {
            int ko = hi * 8;
            b0 = ldf(Bc, wc * 64 + 0 * 16 + la, ko);
            b1 = ldf(Bc, wc * 64 + 1 * 16 + la, ko);
            b2 = ldf(Bc, wc * 64 + 2 * 16 + la, ko);
            b3 = ldf(Bc, wc * 64 + 3 * 16 + la, ko);
            bf16x8 x0 = ldf(Ac, wr * 128 + 0 * 16 + la, ko);
            bf16x8 x1 = ldf(Ac, wr * 128 + 1 * 16 + la, ko);
            bf16x8 x2 = ldf(Ac, wr * 128 + 2 * 16 + la, ko);
            bf16x8 x3 = ldf(Ac, wr * 128 + 3 * 16 + la, ko);
            __builtin_amdgcn_s_setprio(1);
            MFMA_ROW(0, x0) MFMA_ROW(1, x1) MFMA_ROW(2, x2) MFMA_ROW(3, x3)
            __builtin_amdgcn_s_setprio(0);
        }
        __builtin_amdgcn_s_barrier();

        // -------- phase 1: stage A-h1(next); k-half0, m4-7 (b0-3 reused)
        if (pre) stageA(An, kn, 1);
        {
            int ko = hi * 8;
            bf16x8 x4 = ldf(Ac, wr * 128 + 4 * 16 + la, ko);
            bf16x8 x5 = ldf(Ac, wr * 128 + 5 * 16 + la, ko);
            bf16x8 x6 = ldf(Ac, wr * 128 + 6 * 16 + la, ko);
            bf16x8 x7 = ldf(Ac, wr * 128 + 7 * 16 + la, ko);
            __builtin_amdgcn_s_setprio(1);
            MFMA_ROW(4, x4) MFMA_ROW(5, x5) MFMA_ROW(6, x6) MFMA_ROW(7, x7)
            __builtin_amdgcn_s_setprio(0);
        }
        __builtin_amdgcn_s_barrier();

        // -------- phase 2: stage B-h0(next); k-half1, m0-3 (new b0-3)
        if (pre) stageB(Bn, kn, 0);
        {
            int ko = 32 + hi * 8;
            b0 = ldf(Bc, wc * 64 + 0 * 16 + la, ko);
            b1 = ldf(Bc, wc * 64 + 1 * 16 + la, ko);
            b2 = ldf(Bc, wc * 64 + 2 * 16 + la, ko);
            b3 = ldf(Bc, wc * 64 + 3 * 16 + la, ko);
            bf16x8 x0 = ldf(Ac, wr * 128 + 0 * 16 + la, ko);
            bf16x8 x1 = ldf(Ac, wr * 128 + 1 * 16 + la, ko);
            bf16x8 x2 = ldf(Ac, wr * 128 + 2 * 16 + la, ko);
            bf16x8 x3 = ldf(Ac, wr * 128 + 3 * 16 + la, ko);
            __builtin_amdgcn_s_setprio(1);
            MFMA_ROW(0, x0) MFMA_ROW(1, x1) MFMA_ROW(2, x2) MFMA_ROW(3, x3)
            __builtin_amdgcn_s_setprio(0);
        }
        __builtin_amdgcn_s_barrier();

        // -------- phase 3: stage B-h1(next); k-half1, m4-7
        if (pre) stageB(Bn, kn, 1);
        {
            int ko = 32 + hi * 8;
            bf16x8 x4 = ldf(Ac, wr * 128 + 4 * 16 + la, ko);
            bf16x8 x5 = ldf(Ac, wr * 128 + 5 * 16 + la, ko);
            bf16x8 x6 = ldf(Ac, wr * 128 + 6 * 16 + la, ko);
            bf16x8 x7 = ldf(Ac, wr * 128 + 7 * 16 + la, ko);
            __builtin_amdgcn_s_setprio(1);
            MFMA_ROW(4, x4) MFMA_ROW(5, x5) MFMA_ROW(6, x6) MFMA_ROW(7, x7)
            __builtin_amdgcn_s_setprio(0);
        }
        __builtin_amdgcn_s_barrier();
    }
#undef MFMA_ROW

    unsigned short* Ch = C0 + bo * cOuter + bi * cInner;
#pragma unroll
    for (int mi = 0; mi < 8; ++mi) {
#pragma unroll
        for (int ni = 0; ni < 4; ++ni) {
            int gn = n0 + wc * 64 + ni * 16 + la;
            int gmB = m0 + wr * 128 + mi * 16 + hi * 4;
            float bN = 0.f;
            if (EPI == 2 || EPI == 4) bN = biasN[gn];
#pragma unroll
            for (int rr = 0; rr < 4; ++rr) {
                int gm = gmB + rr;
                if (gm >= mValid) continue;
                float v = acc[mi][ni][rr];
                if (EPI == 0) Ch[(long)gm * ldc + gn] = f2bf(v);
                else if (EPI == 2) Ch[(long)gm * ldc + gn] = f2bf(fmaxf(v + bN, 0.f));
                else Ch[(long)gm * ldc + gn] = f2bf(v + bN);
            }
        }
    }
}

// ---------------------------------------------------------------------------
// cross-spectrum * complex weight, IN PLACE on QF. (bh, d, 256) layout.
// ---------------------------------------------------------------------------
__global__ void crossspec(unsigned short* __restrict__ QF, const unsigned short* __restrict__ KF,
                          const float* __restrict__ cw) {
    long idx = (long)blockIdx.x * 256 + threadIdx.x;
    if (idx >= (long)BATCH * NH * DK * NF) return;
    int f = (int)(idx % NF);
    long tq = idx / NF;
    int d = (int)(tq % DK);
    int bh = (int)(tq / DK);
    int h = bh & (NH - 1);
    long base = (long)bh * DK * PD + (long)d * PD;
    float qr = bf2f(QF[base + f]), qi = bf2f(QF[base + NF + f]);
    float kr = bf2f(KF[base + f]), ki = bf2f(KF[base + NF + f]);
    float cr = qr * kr + qi * ki;
    float ci = qi * kr - qr * ki;
    long wb = (((long)h * NF + f) * DK + d) * 2;
    float wr = cw[wb], wi = cw[wb + 1];
    QF[base + f]      = f2bf(cr * wr - ci * wi);
    QF[base + NF + f] = f2bf(cr * wi + ci * wr);
    if (f < PD - NF2) QF[base + NF2 + f] = 0;
}

// ---------------------------------------------------------------------------
// softmax over contiguous s (cols 0..199 of 256), bf16 in -> bf16 out
// ---------------------------------------------------------------------------
__global__ __launch_bounds__(256) void softmax_rows(const unsigned short* __restrict__ in,
                                                    unsigned short* __restrict__ out) {
    long row = (long)blockIdx.x * 4 + (threadIdx.x >> 6);
    int lane = threadIdx.x & 63;
    const unsigned short* p = in + row * PD;
    float v[4];
    float m = -1e30f;
#pragma unroll
    for (int i = 0; i < 4; ++i) {
        int s = lane + 64 * i;
        v[i] = (s < SEQ) ? bf2f(p[s]) : -1e30f;
        m = fmaxf(m, v[i]);
    }
#pragma unroll
    for (int o = 32; o; o >>= 1) m = fmaxf(m, __shfl_xor(m, o));
    float e[4], sum = 0.f;
#pragma unroll
    for (int i = 0; i < 4; ++i) {
        int s = lane + 64 * i;
        e[i] = (s < SEQ) ? expf(v[i] - m) : 0.f;
        sum += e[i];
    }
#pragma unroll
    for (int o = 32; o; o >>= 1) sum += __shfl_xor(sum, o);
    float inv = 1.f / sum;
    unsigned short* q = out + row * PD;
#pragma unroll
    for (int i = 0; i < 4; ++i) {
        int s = lane + 64 * i;
        q[s] = (s < SEQ) ? f2bf(e[i] * inv) : (unsigned short)0;
    }
}

// ---------------------------------------------------------------------------
// gelu(erf) + TF LayerNorm per 1024-wide row (bf16 in, fp32 out)
// ---------------------------------------------------------------------------
__global__ __launch_bounds__(256) void gelu_ln_kernel(const unsigned short* __restrict__ y2,
                               const float* __restrict__ lnw, const float* __restrict__ lnb,
                               float* __restrict__ out) {
    long row = blockIdx.x;
    int tid = threadIdx.x;
    const short4* xr = reinterpret_cast<const short4*>(y2 + row * HID);
    short4 h4 = xr[tid];
    float g[4];
    {
        float x0 = bf2f((unsigned short)h4.x), x1 = bf2f((unsigned short)h4.y);
        float x2 = bf2f((unsigned short)h4.z), x3 = bf2f((unsigned short)h4.w);
        g[0] = 0.5f * x0 * (1.f + erff(x0 * 0.70710678118654752f));
        g[1] = 0.5f * x1 * (1.f + erff(x1 * 0.70710678118654752f));
        g[2] = 0.5f * x2 * (1.f + erff(x2 * 0.70710678118654752f));
        g[3] = 0.5f * x3 * (1.f + erff(x3 * 0.70710678118654752f));
    }

    __shared__ float red[4];
    float s = g[0] + g[1] + g[2] + g[3];
#pragma unroll
    for (int o = 32; o > 0; o >>= 1) s += __shfl_down(s, o);
    if ((tid & 63) == 0) red[tid >> 6] = s;
    __syncthreads();
    float mean = (red[0] + red[1] + red[2] + red[3]) * (1.f / (float)HID);

    float v2 = 0.f;
#pragma unroll
    for (int p = 0; p < 4; ++p) { float d = g[p] - mean; v2 += d * d; }
    __syncthreads();
#pragma unroll
    for (int o = 32; o > 0; o >>= 1) v2 += __shfl_down(v2, o);
    if ((tid & 63) == 0) red[tid >> 6] = v2;
    __syncthreads();
    float var = (red[0] + red[1] + red[2] + red[3]) * (1.f / (float)HID);
    float rstd = rsqrtf(var + 1e-12f);

    float4 o4;
    int i0 = tid * 4;
    o4.x = (g[0] - mean) * rstd * lnw[i0 + 0] + lnb[i0 + 0];
    o4.y = (g[1] - mean) * rstd * lnw[i0 + 1] + lnb[i0 + 1];
    o4.z = (g[2] - mean) * rstd * lnw[i0 + 2] + lnb[i0 + 2];
    o4.w = (g[3] - mean) * rstd * lnw[i0 + 3] + lnb[i0 + 3];
    reinterpret_cast<float4*>(out + row * HID)[tid] = o4;
}

// ---------------------------------------------------------------------------
extern "C" void kernel_launch(void* const* d_in, const int* in_sizes, int n_in,
                              void* d_out, int out_size, void* d_ws, size_t ws_size,
                              hipStream_t stream) {
    const float* query = (const float*)d_in[0];
    const float* key   = (const float*)d_in[1];
    const float* value = (const float*)d_in[2];
    const float* w0 = (const float*)d_in[3];
    const float* w1 = (const float*)d_in[4];
    const float* w2 = (const float*)d_in[5];
    const float* w3 = (const float*)d_in[6];
    const float* attn_bias = (const float*)d_in[7];
    const float* cw = (const float*)d_in[8];
    const float* lw = (const float*)d_in[9];
    const float* lb = (const float*)d_in[10];
    const float* lnw = (const float*)d_in[11];
    const float* lnb = (const float*)d_in[12];
    float* out = (float*)d_out;

    char* base = (char*)d_ws;
    const long BH = (long)BATCH * NH;
    const long SZR = (long)BH * PD * PD;          // elements per 64MiB bf16 region
    const size_t M64 = 67108864;

    unsigned short* F_stack = (unsigned short*)(base + 0);
    unsigned short* G_stack = (unsigned short*)(base + 131072);
    unsigned short* w0T = (unsigned short*)(base + 262144);
    unsigned short* w1T = (unsigned short*)(base + 393216);
    unsigned short* w2T = (unsigned short*)(base + 524288);
    unsigned short* w3b = (unsigned short*)(base + 655360);
    unsigned short* lwb = (unsigned short*)(base + 786432);   // 2MiB
    char* rA = base + 4194304;            // qpT -> corr
    char* rB = rA + M64;                  // kpT -> probs
    char* rC = rB + M64;                  // vpT
    char* rD = rC + M64;                  // QF/R -> alphaT(bf16) -> y2(bf16)
    char* rE = rD + M64;                  // KF   -> X

    unsigned short* qpT = (unsigned short*)rA;
    unsigned short* kpT = (unsigned short*)rB;
    unsigned short* vpT = (unsigned short*)rC;
    unsigned short* QF  = (unsigned short*)rD;
    unsigned short* KF  = (unsigned short*)rE;
    unsigned short* corr = (unsigned short*)rA;
    unsigned short* alphaT = (unsigned short*)rD;
    unsigned short* probs = (unsigned short*)rB;
    unsigned short* X  = (unsigned short*)rE;
    unsigned short* y2 = (unsigned short*)rD;

    const size_t LDS256 = 131072;   // 128KB dynamic LDS for mgemm256

    // tables + weight conversion
    init_tables_bf16<<<256, 256, 0, stream>>>(F_stack, G_stack);
    wtrans256<<<256, 256, 0, stream>>>(w0, w0T);
    wtrans256<<<256, 256, 0, stream>>>(w1, w1T);
    wtrans256<<<256, 256, 0, stream>>>(w2, w2T);
    w3pad<<<256, 256, 0, stream>>>(w3, w3b);
    fconv<<<(HID * HID + 255) / 256, 256, 0, stream>>>(lw, lwb, HID * HID);

    // projections: qpT[bh](d,s) = w0T @ q^T ; B = raw fp32 rows (s<200 valid)
    dim3 gproj(2, 2, BH);
    mgemm128<<<gproj, 256, 0, stream>>>(w0T, query, qpT, DK, DK, HID, PD,
        0L, 0L, (long)SEQ * HID, (long)DK, (long)NH * PD * PD, (long)PD * PD, NH, SEQ);
    mgemm128<<<gproj, 256, 0, stream>>>(w1T, key, kpT, DK, DK, HID, PD,
        0L, 0L, (long)SEQ * HID, (long)DK, (long)NH * PD * PD, (long)PD * PD, NH, SEQ);
    mgemm128<<<gproj, 256, 0, stream>>>(w2T, value, vpT, DK, DK, HID, PD,
        0L, 0L, (long)SEQ * HID, (long)DK, (long)NH * PD * PD, (long)PD * PD, NH, SEQ);

    // forward DFT (q and k batched via bo): QF[bh](d,f) = qpT @ F^T
    mgemm256<0, false><<<dim3(1, 1, 2 * BH), 512, LDS256, stream>>>(
        qpT, F_stack, QF, PD, PD, PD, PD,
        SZR, (long)PD * PD, 0L, 0L, SZR, (long)PD * PD, (int)BH, PD, nullptr);

    // cross-spectrum * weight (in place on QF)
    long ncs = (long)BH * DK * NF;
    crossspec<<<(unsigned)((ncs + 255) / 256), 256, 0, stream>>>(QF, KF, cw);

    // inverse DFT: corr[bh](s,d) = G @ R^T, epilogue relu(+attn_bias over d)
    mgemm256<2, false><<<dim3(1, 1, BH), 512, LDS256, stream>>>(
        G_stack, QF, corr, PD, PD, PD, PD,
        0L, 0L, (long)PD * PD, 0L, (long)PD * PD, 0L, 1, PD, attn_bias);

    // alphaT[bh](l,s) = w3b @ corr^T-form (bf16 out)
    mgemm256<0, false><<<dim3(1, 1, BH), 512, LDS256, stream>>>(
        w3b, corr, alphaT, PD, PD, PD, PD,
        0L, 0L, (long)PD * PD, 0L, (long)PD * PD, 0L, 1, PD, nullptr);

    // softmax over contiguous s
    softmax_rows<<<(unsigned)(BH * PD / 4), 256, 0, stream>>>(alphaT, probs);

    // X[b, l, h*256+d] = probs(l,s) @ vpT(d,s)^T  -- direct, no transpose
    mgemm256<0, false><<<dim3(1, 1, BH), 512, LDS256, stream>>>(
        probs, vpT, X, PD, PD, PD, HID,
        (long)NH * PD * PD, (long)PD * PD,
        (long)NH * PD * PD, (long)PD * PD,
        (long)LS * HID, (long)DK, NH, LS, nullptr);

    // y2 = X @ lw^T + lb : 25600 x 1024 x 1024  (bf16 out, XCD swizzle, 400 wg)
    mgemm256<4, true><<<dim3(HID / 256, (BATCH * LS) / 256, 1), 512, LDS256, stream>>>(
        X, lwb, y2, HID, HID, HID, HID,
        0L, 0L, 0L, 0L, 0L, 0L, 1, BATCH * LS, lb);

    // gelu + LayerNorm
    gelu_ln_kernel<<<(unsigned)(BATCH * LS), 256, 0, stream>>>(y2, lnw, lnb, out);
}